// Round 9
// baseline (329.318 us; speedup 1.0000x reference)
//
#include <hip/hip_runtime.h>

#define NB 128
#define NLQ 256   // sequence length L
#define ND 512    // feature dim D
#define NLAYERS 6
#define DD (ND*ND)
#define MN (1024*ND)
#define HTB 131072   // ushorts per batch per plane: 512*256

typedef short bf16x8 __attribute__((ext_vector_type(8)));
typedef float f32x4 __attribute__((ext_vector_type(4)));
typedef unsigned int u32x2 __attribute__((ext_vector_type(2)));
typedef unsigned short ushort_t;

#define GLOAD16(gp, lp) __builtin_amdgcn_global_load_lds( \
    (const __attribute__((address_space(1))) void*)(gp), \
    (__attribute__((address_space(3))) void*)(lp), 16, 0, 0)

__device__ __forceinline__ float wave_max(float v){
  #pragma unroll
  for(int off=32; off; off>>=1) v = fmaxf(v, __shfl_xor(v, off));
  return v;
}
__device__ __forceinline__ float wave_sum(float v){
  #pragma unroll
  for(int off=32; off; off>>=1) v += __shfl_xor(v, off);
  return v;
}
__device__ __forceinline__ float bfu(ushort_t u){
  return __uint_as_float(((unsigned int)u) << 16);
}

// split two fp32 into packed bf16 hi-plane word and lo-plane word
__device__ __forceinline__ void split2(float x0, float x1, unsigned int& hi, unsigned int& lo){
  unsigned int u0 = __float_as_uint(x0), u1 = __float_as_uint(x1);
  unsigned int h0 = u0 & 0xFFFF0000u, h1 = u1 & 0xFFFF0000u;
  hi = (u0 >> 16) | h1;
  float d0 = x0 - __uint_as_float(h0);
  float d1 = x1 - __uint_as_float(h1);
  lo = (__float_as_uint(d0) >> 16) | (__float_as_uint(d1) & 0xFFFF0000u);
}

__global__ __launch_bounds__(256) void k_scal(const float* __restrict__ a_stack,
                                              float* __restrict__ scal){
  int layer = blockIdx.x;
  const float* a = a_stack + (size_t)layer*2*ND;
  int t = threadIdx.x;
  float v0 = a[t];
  float v1 = a[256 + t];
  v0 = wave_sum(v0); v1 = wave_sum(v1);
  __shared__ float s0[4], s1[4];
  int wave = t>>6, lane = t&63;
  if(lane==0){ s0[wave]=v0; s1[wave]=v1; }
  __syncthreads();
  if(t==0){
    scal[layer*2+0] = s0[0]+s0[1]+s0[2]+s0[3];
    scal[layer*2+1] = s1[0]+s1[1]+s1[2]+s1[3];
  }
}

// v_l[i] = dot(W_{l+1}[i,:], a2_{l+1})
__global__ __launch_bounds__(256) void k_wa2(const float* __restrict__ Wst,
                                             const float* __restrict__ ast,
                                             float* __restrict__ v){
  int l  = blockIdx.x >> 7;
  int rg = blockIdx.x & 127;
  int i  = rg*4 + (threadIdx.x>>6);
  int lane = threadIdx.x & 63;
  const float4* wr = (const float4*)(Wst + (size_t)(l+1)*DD + (size_t)i*ND);
  const float4* ar = (const float4*)(ast + (size_t)(l+1)*2*ND + ND);
  float4 w0=wr[lane], w1=wr[lane+64], a0=ar[lane], a1=ar[lane+64];
  float d = w0.x*a0.x + w0.y*a0.y + w0.z*a0.z + w0.w*a0.w
          + w1.x*a1.x + w1.y*a1.y + w1.z*a1.z + w1.w*a1.w;
  d = wave_sum(d);
  if(lane==0) v[l*ND + i] = d;
}

// ---- split-bf16 MFMA GEMM tile: C[64x128] = A[64x512]@W[512x128] ----
// MODE=0: C row-major [M][512].
// MODE=1: posw fused into A-stage; outputs transposed bf16 planes hiP/loP[b][d][i],
//         Pscore as rounded bf16 (packed into each tile's h1 region),
//         and t-partials tp4[ntile][token].
#define ROWB 80
template<int MODE>
__device__ __forceinline__ void gemm_tile(const float* __restrict__ A,
                                          const float* __restrict__ W,
                                          float* __restrict__ C,
                                          unsigned int* __restrict__ hiP,
                                          unsigned int* __restrict__ loP,
                                          ushort_t* __restrict__ Pbuf,
                                          float* __restrict__ tp4,
                                          const float* __restrict__ a2,
                                          const float* __restrict__ scal,
                                          const int* __restrict__ left,
                                          const int* __restrict__ asp,
                                          const int* __restrict__ tl,
                                          int mtile, int ntile, unsigned char* lds){
  unsigned char* Ahi = lds;                              // 64*80
  unsigned char* Alo = lds + 64*ROWB;                    // 64*80
  unsigned char* Bhi = lds + 2*64*ROWB;                  // 128*80
  unsigned char* Blo = lds + 2*64*ROWB + 128*ROWB;       // 128*80

  int t = threadIdx.x;
  int m0 = mtile*64, n0 = ntile*128;
  int lane = t & 63, wid = t >> 6;
  int wr = wid >> 1, wc = wid & 1;
  int lrow = lane & 15, kb = lane >> 4;

  f32x4 acc[2][4];
  #pragma unroll
  for(int mi=0;mi<2;mi++)
    #pragma unroll
    for(int ni=0;ni<4;ni++)
      acc[mi][ni] = (f32x4){0.f,0.f,0.f,0.f};

  int a_row = t >> 3;          // 0..31 (+p*32)
  int a_kq  = t & 7;
  int w_n   = t & 127;
  int w_half= t >> 7;

  float wgt_[2] = {1.f,1.f};
  if(MODE == 1){
    int b = mtile >> 2;
    float lf=(float)left[b], aspf=(float)asp[b], tlf=(float)tl[b];
    float rr=lf+aspf-1.f, ctx=tlf-aspf;
    #pragma unroll
    for(int p=0;p<2;p++){
      float jf = (float)((mtile&3)*64 + a_row + p*32);
      float w;
      if(jf < lf)       w = 1.f-(lf-jf)/ctx;
      else if(jf <= rr) w = 0.f;
      else if(jf < tlf) w = 1.f-(jf-rr)/ctx;
      else              w = 0.f;
      wgt_[p] = w;
    }
  }

  float4 pa[2];
  float  pw[16];

  #pragma unroll
  for(int p=0;p<2;p++)
    pa[p] = *(const float4*)(A + (size_t)(m0 + a_row + p*32)*ND + a_kq*4);
  #pragma unroll
  for(int q=0;q<4;q++){
    const float* wp = W + (size_t)(w_half*16 + q*4)*ND + n0 + w_n;
    pw[q*4+0]=wp[0]; pw[q*4+1]=wp[ND]; pw[q*4+2]=wp[2*ND]; pw[q*4+3]=wp[3*ND];
  }

  for(int k0=0; k0<ND; k0+=32){
    #pragma unroll
    for(int p=0;p<2;p++){
      int row = a_row + p*32;
      unsigned int h01, l01, h23, l23;
      split2(pa[p].x*wgt_[p], pa[p].y*wgt_[p], h01, l01);
      split2(pa[p].z*wgt_[p], pa[p].w*wgt_[p], h23, l23);
      int off = row*ROWB + a_kq*8;
      *(u32x2*)(Ahi + off) = (u32x2){h01, h23};
      *(u32x2*)(Alo + off) = (u32x2){l01, l23};
    }
    #pragma unroll
    for(int q=0;q<4;q++){
      unsigned int h01, l01, h23, l23;
      split2(pw[q*4+0], pw[q*4+1], h01, l01);
      split2(pw[q*4+2], pw[q*4+3], h23, l23);
      int off = w_n*ROWB + (w_half*4 + q)*8;
      *(u32x2*)(Bhi + off) = (u32x2){h01, h23};
      *(u32x2*)(Blo + off) = (u32x2){l01, l23};
    }
    __syncthreads();

    if(k0 + 32 < ND){
      int kn = k0 + 32;
      #pragma unroll
      for(int p=0;p<2;p++)
        pa[p] = *(const float4*)(A + (size_t)(m0 + a_row + p*32)*ND + kn + a_kq*4);
      #pragma unroll
      for(int q=0;q<4;q++){
        const float* wp = W + (size_t)(kn + w_half*16 + q*4)*ND + n0 + w_n;
        pw[q*4+0]=wp[0]; pw[q*4+1]=wp[ND]; pw[q*4+2]=wp[2*ND]; pw[q*4+3]=wp[3*ND];
      }
    }

    bf16x8 ah[2], al[2], bh[4], bl[4];
    #pragma unroll
    for(int mi=0;mi<2;mi++){
      int r = wr*32 + mi*16 + lrow;
      int off = r*ROWB + kb*16;
      ah[mi] = *(const bf16x8*)(Ahi + off);
      al[mi] = *(const bf16x8*)(Alo + off);
    }
    #pragma unroll
    for(int ni=0;ni<4;ni++){
      int n = wc*64 + ni*16 + lrow;
      int off = n*ROWB + kb*16;
      bh[ni] = *(const bf16x8*)(Bhi + off);
      bl[ni] = *(const bf16x8*)(Blo + off);
    }

    #pragma unroll
    for(int mi=0;mi<2;mi++)
      #pragma unroll
      for(int ni=0;ni<4;ni++){
        acc[mi][ni] = __builtin_amdgcn_mfma_f32_16x16x32_bf16(ah[mi], bh[ni], acc[mi][ni], 0,0,0);
        acc[mi][ni] = __builtin_amdgcn_mfma_f32_16x16x32_bf16(ah[mi], bl[ni], acc[mi][ni], 0,0,0);
        acc[mi][ni] = __builtin_amdgcn_mfma_f32_16x16x32_bf16(al[mi], bh[ni], acc[mi][ni], 0,0,0);
      }
    __syncthreads();
  }

  int rg = lane >> 4;
  int cc = lane & 15;
  if(MODE == 0){
    #pragma unroll
    for(int mi=0;mi<2;mi++)
      #pragma unroll
      for(int ni=0;ni<4;ni++){
        int col = n0 + wc*64 + ni*16 + cc;
        #pragma unroll
        for(int q=0;q<4;q++){
          int row = m0 + wr*32 + mi*16 + rg*4 + q;
          C[(size_t)row*ND + col] = acc[mi][ni][q];
        }
      }
  } else {
    float S0 = scal[0], S1 = scal[1];
    float* CT = (float*)lds;   // [64 cols][stride 66] floats = 16896 B (fits staging LDS)
    int b = mtile >> 2;
    int ibase = (mtile & 3) * 64;
    int tr = t >> 2, tch = t & 3;
    float tpsum = 0.f;
    #pragma unroll
    for(int p=0;p<2;p++){
      if(wc == p){
        #pragma unroll
        for(int mi=0;mi<2;mi++)
          #pragma unroll
          for(int ni=0;ni<4;ni++)
            #pragma unroll
            for(int q=0;q<4;q++)
              CT[(ni*16+cc)*66 + wr*32 + mi*16 + rg*4 + q] = acc[mi][ni][q];
      }
      __syncthreads();
      // transposed bf16 planes [b][d][i]
      #pragma unroll
      for(int u=0;u<8;u++){
        int idx = t + u*256;           // 0..2047
        int c = idx >> 5, rp = idx & 31;
        float v0 = CT[c*66 + 2*rp];
        float v1 = CT[c*66 + 2*rp + 1];
        unsigned int hi, lo;
        split2(v0, v1, hi, lo);
        size_t uidx = ((size_t)b*HTB + (size_t)(n0 + p*64 + c)*256 + ibase + 2*rp) >> 1;
        hiP[uidx] = hi;
        loP[uidx] = lo;
      }
      // Pscore: pair-reduced scores, rounded bf16, packed into the (b,itile) h1 region
      #pragma unroll
      for(int u=0;u<8;u++){
        int idx = t + u*256;
        int pj = idx & 31, i = idx >> 5;    // i 0..63
        float pval = S0*CT[(2*pj)*66 + i] + S1*CT[(2*pj+1)*66 + i];
        int ig = ibase + i;
        unsigned int pb = __float_as_uint(pval);
        ushort_t po = (ushort_t)((pb + 0x7FFFu + ((pb>>16)&1u)) >> 16);
        size_t addr = (size_t)b*262144 + (size_t)(ig>>5)*32768
                    + (size_t)(ig&31)*256 + (n0>>1) + p*32 + pj;
        Pbuf[addr] = po;
      }
      // t-partial over this 64-d slab
      #pragma unroll
      for(int cc2=0; cc2<16; cc2++){
        int c = tch*16 + cc2;
        tpsum = fmaf(CT[c*66 + tr], a2[n0 + p*64 + c], tpsum);
      }
      __syncthreads();
    }
    tpsum += __shfl_xor(tpsum, 1);
    tpsum += __shfl_xor(tpsum, 2);
    if(tch == 0) tp4[(n0>>7)*32768 + m0 + tr] = tpsum;
  }
}

__global__ __launch_bounds__(256) void k_gemm_t(const float* __restrict__ A,
                                                const float* __restrict__ W,
                                                unsigned int* __restrict__ hiP,
                                                unsigned int* __restrict__ loP,
                                                ushort_t* __restrict__ Pbuf,
                                                float* __restrict__ tp4,
                                                const float* __restrict__ a2,
                                                const float* __restrict__ scal,
                                                const int* __restrict__ left,
                                                const int* __restrict__ asp,
                                                const int* __restrict__ tl){
  __shared__ unsigned char lds[2*64*ROWB + 2*128*ROWB];
  // XCD swizzle: 4 n-tiles of each m-tile within 32 consecutive bids, all same (bid mod 8)
  int bid = blockIdx.x;
  int ntile = (bid >> 3) & 3;
  int mtile = (bid & 7) | ((bid >> 5) << 3);
  gemm_tile<1>(A, W, nullptr, hiP, loP, Pbuf, tp4, a2, scal, left, asp, tl,
               mtile, ntile, lds);
}

__global__ __launch_bounds__(256) void k_gemm_b(const float* __restrict__ Abase, long aStride,
                                                const float* __restrict__ Wbase,
                                                float* __restrict__ Cbase){
  __shared__ unsigned char lds[2*64*ROWB + 2*128*ROWB];
  int l  = blockIdx.x >> 6;      // 64 tiles per layer (16 m x 4 n)
  int tb = blockIdx.x & 63;
  gemm_tile<0>(Abase + (size_t)l*aStride, Wbase + (size_t)(l+1)*DD,
               Cbase + (size_t)l*MN, nullptr, nullptr, nullptr, nullptr, nullptr,
               nullptr, nullptr, nullptr, nullptr, tb>>2, tb&3, lds);
}

// layer-0 attention: coalesced bf16-P softmax (lanes=j, adj direct int4)
// + MFMA aggregation with global_load_lds-staged B planes.
__global__ __launch_bounds__(256) void k_attn0(
    const ushort_t* __restrict__ hTH, const ushort_t* __restrict__ hTL,
    const int* __restrict__ adj,
    const float* __restrict__ tpart,
    const int* __restrict__ left, const int* __restrict__ asp, const int* __restrict__ tl,
    float* __restrict__ PA){
  __shared__ unsigned char attH[32*512];   // bf16 hi plane [32 i][256 j], XOR-swizzled
  __shared__ unsigned char attL[32*512];
  __shared__ unsigned char BsH[16384];     // staged hi plane [256 d][32 j] linear 64B rows
  __shared__ unsigned char BsL[16384];

  int bid = blockIdx.x;
  int b  = bid & 127;      // 8 blocks of batch b land on same XCD
  int ic = bid >> 7;
  int i0 = ic*32;
  int tid = threadIdx.x;
  int lane = tid & 63, w = tid >> 6;
  const ushort_t* HH = hTH + (size_t)b*HTB;
  const ushort_t* HL = hTL + (size_t)b*HTB;
  const ushort_t* Pt = (const ushort_t*)PA + (size_t)b*262144 + (size_t)ic*32768;

  // ---- phase 1: softmax, lanes = j (4 j's per lane) ----
  float t0v=0.f, t1v=0.f, t2v=0.f, t3v=0.f;
  #pragma unroll
  for(int nt=0; nt<4; nt++){
    float4 tv = ((const float4*)(tpart + nt*32768 + b*256))[lane];
    t0v += tv.x; t1v += tv.y; t2v += tv.z; t3v += tv.w;
  }

  for(int rr=0; rr<8; rr++){
    int il = w*8 + rr;         // 0..31
    int i  = i0 + il;
    u32x2 pw = *(const u32x2*)(Pt + il*256 + lane*4);
    float pv0 = bfu((ushort_t)(pw[0] & 0xFFFFu));
    float pv1 = bfu((ushort_t)(pw[0] >> 16));
    float pv2 = bfu((ushort_t)(pw[1] & 0xFFFFu));
    float pv3 = bfu((ushort_t)(pw[1] >> 16));
    int4 av = ((const int4*)(adj + ((size_t)b*NLQ + i)*NLQ))[lane];
    float e0 = fmaxf(pv0 + t0v, 0.f);
    float e1 = fmaxf(pv1 + t1v, 0.f);
    float e2 = fmaxf(pv2 + t2v, 0.f);
    float e3 = fmaxf(pv3 + t3v, 0.f);
    float m = -3.0e38f;
    if(av.x>0) m = e0;
    if(av.y>0) m = fmaxf(m, e1);
    if(av.z>0) m = fmaxf(m, e2);
    if(av.w>0) m = fmaxf(m, e3);
    m = wave_max(m);
    float p0 = (av.x>0) ? __expf(e0-m) : 0.f;
    float p1 = (av.y>0) ? __expf(e1-m) : 0.f;
    float p2 = (av.z>0) ? __expf(e2-m) : 0.f;
    float p3 = (av.w>0) ? __expf(e3-m) : 0.f;
    float s = wave_sum(p0+p1+p2+p3);
    float inv = 1.f/s;
    unsigned int h0,l0,h1v,l1;
    split2(p0*inv, p1*inv, h0, l0);
    split2(p2*inv, p3*inv, h1v, l1);
    int off = il*512 + ((lane*8) ^ ((il&7)<<4));
    *(u32x2*)(attH + off) = (u32x2){h0,h1v};
    *(u32x2*)(attL + off) = (u32x2){l0,l1};
  }

  // ---- phase 2: O[i][d] = att @ h via MFMA; B staged via global_load_lds ----
  int wm = w >> 1, wn = w & 1;
  int lrow = lane & 15, kb = lane >> 4;
  int rg = lane >> 4, cc = lane & 15;
  float lf=(float)left[b], aspf=(float)asp[b], tlf=(float)tl[b];
  float rrv=lf+aspf-1.f, ctx=tlf-aspf;
  int arow = wm*16 + lrow;
  int aswz = (arow&7)<<4;

  for(int dp=0; dp<2; dp++){
    int d0 = dp*256;
    f32x4 acc[8];
    #pragma unroll
    for(int ni=0;ni<8;ni++) acc[ni] = (f32x4){0.f,0.f,0.f,0.f};
    for(int ks=0; ks<8; ks++){
      int j0 = ks*32;
      __syncthreads();   // previous tile fully consumed (also orders att writes)
      #pragma unroll
      for(int u=0;u<4;u++){
        int chunk = (u*4 + w)*64 + lane;
        int row = chunk >> 2, sl = chunk & 3;
        const ushort_t* gph = HH + (size_t)(d0+row)*256 + j0 + sl*8;
        const ushort_t* gpl = HL + (size_t)(d0+row)*256 + j0 + sl*8;
        GLOAD16(gph, BsH + (u*4+w)*1024);
        GLOAD16(gpl, BsL + (u*4+w)*1024);
      }
      __syncthreads();   // loads landed
      int aoff = arow*512 + ((j0*2 + kb*16) ^ aswz);
      bf16x8 ah = *(const bf16x8*)(attH + aoff);
      bf16x8 al = *(const bf16x8*)(attL + aoff);
      #pragma unroll
      for(int ni=0; ni<8; ni++){
        int boff = (wn*128 + ni*16 + lrow)*64 + kb*16;
        bf16x8 bh = *(const bf16x8*)(BsH + boff);
        bf16x8 bl = *(const bf16x8*)(BsL + boff);
        acc[ni] = __builtin_amdgcn_mfma_f32_16x16x32_bf16(ah, bh, acc[ni], 0,0,0);
        acc[ni] = __builtin_amdgcn_mfma_f32_16x16x32_bf16(ah, bl, acc[ni], 0,0,0);
        acc[ni] = __builtin_amdgcn_mfma_f32_16x16x32_bf16(al, bh, acc[ni], 0,0,0);
      }
    }
    #pragma unroll
    for(int q=0;q<4;q++){
      int row = i0 + wm*16 + rg*4 + q;
      float fi = (float)row;
      float wgt;
      if(fi < lf)        wgt = 1.f-(lf-fi)/ctx;
      else if(fi <= rrv) wgt = 0.f;
      else if(fi < tlf)  wgt = 1.f-(fi-rrv)/ctx;
      else               wgt = 0.f;
      #pragma unroll
      for(int ni=0;ni<8;ni++){
        int col = d0 + wn*128 + ni*16 + cc;
        PA[((size_t)b*NLQ + row)*ND + col] = wgt*fmaxf(acc[ni][q], 0.f);
      }
    }
  }
}

// T[l][b*256+j] = h1[b,j,:] . v_l
__global__ __launch_bounds__(256) void k_tv(const float* __restrict__ h1,
                                            const float* __restrict__ v,
                                            float* __restrict__ T){
  int row  = blockIdx.x*4 + (threadIdx.x>>6);
  int lane = threadIdx.x & 63;
  const float4* hr = (const float4*)(h1 + (size_t)row*ND);
  float4 h0 = hr[lane], h1v = hr[lane+64];
  float s0,s1,s2,s3,s4;
  #define DOTV(SL, L) { \
    const float4* vr = (const float4*)(v + (L)*ND); \
    float4 v0 = vr[lane], v1 = vr[lane+64]; \
    float dd = h0.x*v0.x+h0.y*v0.y+h0.z*v0.z+h0.w*v0.w \
             + h1v.x*v1.x+h1v.y*v1.y+h1v.z*v1.z+h1v.w*v1.w; \
    SL = wave_sum(dd); }
  DOTV(s0,0) DOTV(s1,1) DOTV(s2,2) DOTV(s3,3) DOTV(s4,4)
  #undef DOTV
  if(lane==0){
    T[0*32768 + row]=s0; T[1*32768 + row]=s1; T[2*32768 + row]=s2;
    T[3*32768 + row]=s3; T[4*32768 + row]=s4;
  }
}

__global__ __launch_bounds__(256) void k_rows(const float* __restrict__ h1,
                                              const int* __restrict__ left, const int* __restrict__ asp,
                                              float* __restrict__ R){
  int b = blockIdx.x;
  int nk = asp[b], l0 = left[b];
  const float4* src = (const float4*)(h1 + (size_t)b*NLQ*ND);
  float4* dst = (float4*)(R + (size_t)b*8*ND);
  #pragma unroll
  for(int u=0; u<4; u++){
    int f4 = threadIdx.x + u*256;
    int k = f4 >> 7, c = f4 & 127;
    float4 val = (k<nk) ? src[(size_t)(l0+k)*128 + c] : (float4){0.f,0.f,0.f,0.f};
    dst[f4] = val;
  }
}

// all 25 (layer,row) atts for one batch; y = att @ h1. 2 blocks per b (d halves).
__global__ __launch_bounds__(256) void k_att5(const float* __restrict__ h1,
    const float* __restrict__ Hasp, const float* __restrict__ T,
    const int* __restrict__ adj, const float* __restrict__ scal,
    const int* __restrict__ left, const int* __restrict__ asp,
    float* __restrict__ y){
  __shared__ float att[25][260];
  int b  = blockIdx.x & 127;
  int dh = blockIdx.x >> 7;
  int tid = threadIdx.x, lane = tid&63, w = tid>>6;
  int nk = asp[b], l0 = left[b];

  for(int r = w; r < 25; r += 4){
    int l = r/5, k = r - l*5;
    if(k < nk){
      float S0 = scal[2*(l+1)], S1 = scal[2*(l+1)+1];
      const float2* hrow = (const float2*)(Hasp + (size_t)l*MN + (size_t)(b*8+k)*ND);
      const int* arow = adj + ((size_t)b*NLQ + (l0+k))*NLQ;
      const float* Tl = T + l*32768 + b*256;
      float e[4]; int av[4];
      float m = -3.0e38f;
      #pragma unroll
      for(int q=0;q<4;q++){
        int j = lane + 64*q;
        float2 hp = hrow[j];
        av[q] = arow[j];
        e[q] = fmaxf(S0*hp.x + S1*hp.y + Tl[j], 0.f);
        if(av[q] > 0) m = fmaxf(m, e[q]);
      }
      m = wave_max(m);
      float pp[4]; float s = 0.f;
      #pragma unroll
      for(int q=0;q<4;q++){
        pp[q] = (av[q] > 0) ? __expf(e[q]-m) : 0.f;
        s += pp[q];
      }
      s = wave_sum(s);
      float inv = 1.f/s;
      #pragma unroll
      for(int q=0;q<4;q++) att[r][lane+64*q] = pp[q]*inv;
    } else {
      #pragma unroll
      for(int q=0;q<4;q++) att[r][lane+64*q] = 0.f;
    }
  }
  __syncthreads();

  int d = dh*256 + tid;
  const float* hb = h1 + (size_t)b*NLQ*ND;
  float acc[25];
  #pragma unroll
  for(int r=0;r<25;r++) acc[r]=0.f;
  for(int jj=0; jj<NLQ; jj++){
    float hv = hb[(size_t)jj*ND + d];
    #pragma unroll
    for(int r=0;r<25;r++) acc[r] += att[r][jj]*hv;
  }
  #pragma unroll
  for(int r=0;r<25;r++){
    int l = r/5, k = r - l*5;
    y[(size_t)l*MN + ((size_t)b*8+k)*ND + d] = acc[r];
  }
  #pragma unroll
  for(int l=0;l<5;l++)
    #pragma unroll
    for(int k=5;k<8;k++)
      y[(size_t)l*MN + ((size_t)b*8+k)*ND + d] = 0.f;
}

__global__ __launch_bounds__(256) void k_g(const float* __restrict__ hp,
    const int* __restrict__ asp, float* __restrict__ g){
  int b = blockIdx.x, d = threadIdx.x;
  int nk = asp[b];
  float gx=0.f, gy=0.f;
  for(int l=0;l<5;l++){
    for(int k=0;k<nk;k++){
      const float* r = hp + (size_t)l*MN + (size_t)(b*8+k)*ND;
      gx += fmaxf(r[d], 0.f);
      gy += fmaxf(r[d+256], 0.f);
    }
  }
  g[b*ND + d]       = 0.2f*gx;
  g[b*ND + 256 + d] = 0.2f*gy;
}

__global__ __launch_bounds__(256) void k_dot(const float* __restrict__ x,
    const float* __restrict__ g, float* __restrict__ s){
  int row  = blockIdx.x*4 + (threadIdx.x>>6);
  int b    = row >> 8;
  int lane = threadIdx.x & 63;
  const float4* xr = (const float4*)(x + (size_t)row*ND);
  const float4* gr = (const float4*)(g + (size_t)b*ND);
  float4 x0=xr[lane], x1=xr[lane+64], g0=gr[lane], g1=gr[lane+64];
  float d = x0.x*g0.x + x0.y*g0.y + x0.z*g0.z + x0.w*g0.w
          + x1.x*g1.x + x1.y*g1.y + x1.z*g1.z + x1.w*g1.w;
  d = wave_sum(d);
  if(lane==0) s[row] = d;
}

__global__ __launch_bounds__(256) void k_out(const float* __restrict__ x,
    const float* __restrict__ s, float* __restrict__ out){
  int b  = blockIdx.x >> 2;
  int ch = blockIdx.x & 3;
  int tid = threadIdx.x, lane = tid&63, w = tid>>6;
  __shared__ float red[4];
  __shared__ float alpha[NLQ];
  __shared__ float part[128];
  float sv = s[b*NLQ + tid];
  float m = wave_max(sv);
  if(lane==0) red[w] = m;
  __syncthreads();
  m = fmaxf(fmaxf(red[0],red[1]), fmaxf(red[2],red[3]));
  float p = __expf(sv - m);
  float su = wave_sum(p);
  __syncthreads();
  if(lane==0) red[w] = su;
  __syncthreads();
  su = red[0]+red[1]+red[2]+red[3];
  alpha[tid] = p/su;
  __syncthreads();
  int d = ch*128 + (tid & 127);
  int half = tid >> 7;
  const float* xb = x + (size_t)b*NLQ*ND;
  float acc = 0.f;
  for(int mm = half*128; mm < half*128 + 128; mm++)
    acc += alpha[mm] * xb[(size_t)mm*ND + d];
  if(half) part[tid & 127] = acc;
  __syncthreads();
  if(!half) out[(size_t)b*ND + d] = acc + part[tid & 127];
}

extern "C" void kernel_launch(void* const* d_in, const int* in_sizes, int n_in,
                              void* d_out, int out_size, void* d_ws, size_t ws_size,
                              hipStream_t stream){
  const float* x    = (const float*)d_in[0];
  const float* Wst  = (const float*)d_in[1];
  const float* ast  = (const float*)d_in[2];
  const int*   adj  = (const int*)d_in[3];
  const int*   left = (const int*)d_in[4];
  const int*   asp  = (const int*)d_in[5];
  const int*   tl   = (const int*)d_in[6];
  float* out = (float*)d_out;
  float* ws  = (float*)d_ws;

  const size_t SZ = (size_t)NB*NLQ*ND;
  float* bufA = ws;                     // P (bf16, packed per tile) -> h1 (block-local overwrite)
  float* bufB = ws + SZ;                // bf16 planes; later Hasp/ybuf/hp/R
  float* ws2  = ws + 2*SZ;
  float* tpart= ws2;                    // 4*32768
  float* T    = tpart + 4*32768;        // 163840
  float* g    = T + 163840;             // 65536
  float* scal = g + 65536;              // 16
  float* v    = scal + 16;              // 2560
  float* sbuf = v + 2560;               // 32768

  ushort_t* hTH = (ushort_t*)bufB;
  ushort_t* hTL = hTH + (size_t)NB*HTB;

  float* Hasp = bufB;                   // reuse after k_attn0
  float* ybuf = Hasp + (size_t)5*MN;
  float* hp   = ybuf + (size_t)5*MN;
  float* R    = hp   + (size_t)5*MN;

  k_scal<<<NLAYERS, 256, 0, stream>>>(ast, scal);
  k_wa2<<<5*128, 256, 0, stream>>>(Wst, ast, v);

  // layer 0: posw fused in A-stage; emits bf16 planes + bf16 pair-scores P + t-partials
  k_gemm_t<<<(NB*NLQ/64)*(ND/128), 256, 0, stream>>>(x, Wst,
      (unsigned int*)hTH, (unsigned int*)hTL, (ushort_t*)bufA, tpart, ast + ND,
      scal, left, asp, tl);
  k_attn0<<<NB*8, 256, 0, stream>>>(hTH, hTL, adj, tpart, left, asp, tl, bufA);

  // layers 1..5 on aspect rows only
  k_tv<<<NB*NLQ/4, 256, 0, stream>>>(bufA, v, T);
  k_rows<<<NB, 256, 0, stream>>>(bufA, left, asp, R);
  k_gemm_b<<<5*64, 256, 0, stream>>>(R, 0L, Wst, Hasp);
  k_att5<<<NB*2, 256, 0, stream>>>(bufA, Hasp, T, adj, scal, left, asp, ybuf);
  k_gemm_b<<<5*64, 256, 0, stream>>>(ybuf, (long)MN, Wst, hp);
  k_g<<<NB, 256, 0, stream>>>(hp, asp, g);

  // final attention over original x
  k_dot<<<NB*NLQ/4, 256, 0, stream>>>(x, g, sbuf);
  k_out<<<NB*4, 256, 0, stream>>>(x, sbuf, out);
}

// Round 10
// 324.678 us; speedup vs baseline: 1.0143x; 1.0143x over previous
//
#include <hip/hip_runtime.h>

#define NB 128
#define NLQ 256   // sequence length L
#define ND 512    // feature dim D
#define NLAYERS 6
#define DD (ND*ND)
#define MN (1024*ND)
#define HTB 131072   // ushorts per batch per plane: 512*256

typedef short bf16x8 __attribute__((ext_vector_type(8)));
typedef float f32x4 __attribute__((ext_vector_type(4)));
typedef unsigned int u32x2 __attribute__((ext_vector_type(2)));
typedef unsigned int u32x4 __attribute__((ext_vector_type(4)));
typedef unsigned short ushort_t;

#define GLOAD16(gp, lp) __builtin_amdgcn_global_load_lds( \
    (const __attribute__((address_space(1))) void*)(gp), \
    (__attribute__((address_space(3))) void*)(lp), 16, 0, 0)

__device__ __forceinline__ float wave_max(float v){
  #pragma unroll
  for(int off=32; off; off>>=1) v = fmaxf(v, __shfl_xor(v, off));
  return v;
}
__device__ __forceinline__ float wave_sum(float v){
  #pragma unroll
  for(int off=32; off; off>>=1) v += __shfl_xor(v, off);
  return v;
}
__device__ __forceinline__ float bfu(ushort_t u){
  return __uint_as_float(((unsigned int)u) << 16);
}

// split two fp32 into packed bf16 hi-plane word and lo-plane word
__device__ __forceinline__ void split2(float x0, float x1, unsigned int& hi, unsigned int& lo){
  unsigned int u0 = __float_as_uint(x0), u1 = __float_as_uint(x1);
  unsigned int h0 = u0 & 0xFFFF0000u, h1 = u1 & 0xFFFF0000u;
  hi = (u0 >> 16) | h1;
  float d0 = x0 - __uint_as_float(h0);
  float d1 = x1 - __uint_as_float(h1);
  lo = (__float_as_uint(d0) >> 16) | (__float_as_uint(d1) & 0xFFFF0000u);
}

// pack two fp32 into one word of round-to-nearest bf16
__device__ __forceinline__ unsigned int pack2_bf16(float a, float b){
  unsigned int ua = __float_as_uint(a), ub = __float_as_uint(b);
  ua = (ua + 0x7FFFu + ((ua>>16)&1u)) >> 16;
  ub = (ub + 0x7FFFu + ((ub>>16)&1u)) & 0xFFFF0000u;
  return ua | ub;
}

__global__ __launch_bounds__(256) void k_scal(const float* __restrict__ a_stack,
                                              float* __restrict__ scal){
  int layer = blockIdx.x;
  const float* a = a_stack + (size_t)layer*2*ND;
  int t = threadIdx.x;
  float v0 = a[t];
  float v1 = a[256 + t];
  v0 = wave_sum(v0); v1 = wave_sum(v1);
  __shared__ float s0[4], s1[4];
  int wave = t>>6, lane = t&63;
  if(lane==0){ s0[wave]=v0; s1[wave]=v1; }
  __syncthreads();
  if(t==0){
    scal[layer*2+0] = s0[0]+s0[1]+s0[2]+s0[3];
    scal[layer*2+1] = s1[0]+s1[1]+s1[2]+s1[3];
  }
}

// v_l[i] = dot(W_{l+1}[i,:], a2_{l+1})
__global__ __launch_bounds__(256) void k_wa2(const float* __restrict__ Wst,
                                             const float* __restrict__ ast,
                                             float* __restrict__ v){
  int l  = blockIdx.x >> 7;
  int rg = blockIdx.x & 127;
  int i  = rg*4 + (threadIdx.x>>6);
  int lane = threadIdx.x & 63;
  const float4* wr = (const float4*)(Wst + (size_t)(l+1)*DD + (size_t)i*ND);
  const float4* ar = (const float4*)(ast + (size_t)(l+1)*2*ND + ND);
  float4 w0=wr[lane], w1=wr[lane+64], a0=ar[lane], a1=ar[lane+64];
  float d = w0.x*a0.x + w0.y*a0.y + w0.z*a0.z + w0.w*a0.w
          + w1.x*a1.x + w1.y*a1.y + w1.z*a1.z + w1.w*a1.w;
  d = wave_sum(d);
  if(lane==0) v[l*ND + i] = d;
}

// transpose + split W layers into bf16 planes Wt[n][k] (hi/lo). One 64x64 tile per block.
__global__ __launch_bounds__(256) void k_wsplit(const float* __restrict__ Wsrc,
                                                ushort_t* __restrict__ Ho,
                                                ushort_t* __restrict__ Lo){
  __shared__ float CT[64][65];
  int bid = blockIdx.x;
  int l  = bid >> 6;
  int kt = (bid >> 3) & 7, nt = bid & 7;
  const float* Wl = Wsrc + (size_t)l*DD;
  int t = threadIdx.x;
  int r = t >> 2, c4 = (t&3)*16;
  #pragma unroll
  for(int u=0;u<4;u++){
    float4 vv = *(const float4*)(Wl + (size_t)(kt*64+r)*ND + nt*64 + c4 + u*4);
    CT[r][c4+u*4+0]=vv.x; CT[r][c4+u*4+1]=vv.y;
    CT[r][c4+u*4+2]=vv.z; CT[r][c4+u*4+3]=vv.w;
  }
  __syncthreads();
  int n = t >> 2, kc = t & 3;
  unsigned int oh[8], ol[8];
  #pragma unroll
  for(int j=0;j<8;j++){
    float a = CT[kc*16 + 2*j][n];
    float b = CT[kc*16 + 2*j + 1][n];
    split2(a, b, oh[j], ol[j]);
  }
  ushort_t* dh = Ho + (size_t)l*DD + (size_t)(nt*64+n)*ND + kt*64 + kc*16;
  ushort_t* dl = Lo + (size_t)l*DD + (size_t)(nt*64+n)*ND + kt*64 + kc*16;
  *(u32x4*)(dh)     = (u32x4){oh[0],oh[1],oh[2],oh[3]};
  *(u32x4*)(dh + 8) = (u32x4){oh[4],oh[5],oh[6],oh[7]};
  *(u32x4*)(dl)     = (u32x4){ol[0],ol[1],ol[2],ol[3]};
  *(u32x4*)(dl + 8) = (u32x4){ol[4],ol[5],ol[6],ol[7]};
}

// ---- split-bf16 MFMA GEMM tile: C[128x128] = A[128x512]@W[512x128] ----
// W comes pre-split/transposed as planes Wt[n][k]. A is fp32, split in staging.
// MODE=0: C row-major [M][512].
// MODE=1: posw fused into A-stage; outputs transposed bf16 planes hiP/loP[b][d][i],
//         Pscore as rounded bf16 (packed per tile), t-partials tp4.
#define ROWB 80
template<int MODE>
__device__ __forceinline__ void gemm_tile(const float* __restrict__ A,
                                          const ushort_t* __restrict__ Wth,
                                          const ushort_t* __restrict__ Wtl,
                                          float* __restrict__ C,
                                          unsigned int* __restrict__ hiP,
                                          unsigned int* __restrict__ loP,
                                          ushort_t* __restrict__ Pbuf,
                                          float* __restrict__ tp4,
                                          const float* __restrict__ a2,
                                          const float* __restrict__ scal,
                                          const int* __restrict__ left,
                                          const int* __restrict__ asp,
                                          const int* __restrict__ tl,
                                          int mtile, int ntile, unsigned char* lds){
  unsigned char* Ahi = lds;
  unsigned char* Alo = lds + 128*ROWB;
  unsigned char* Bhi = lds + 2*128*ROWB;
  unsigned char* Blo = lds + 3*128*ROWB;

  int t = threadIdx.x;
  int m0 = mtile*128, n0 = ntile*128;
  int lane = t & 63, wid = t >> 6;
  int wr = wid >> 1, wc = wid & 1;
  int lrow = lane & 15, kb = lane >> 4;

  f32x4 acc[4][4];
  #pragma unroll
  for(int mi=0;mi<4;mi++)
    #pragma unroll
    for(int ni=0;ni<4;ni++)
      acc[mi][ni] = (f32x4){0.f,0.f,0.f,0.f};

  int a_row = t >> 3;
  int a_kq  = t & 7;
  int w_n   = t >> 2;       // 0..63
  int w_kc  = t & 3;

  float wgt_[4] = {1.f,1.f,1.f,1.f};
  if(MODE == 1){
    int b = mtile >> 1;
    float lf=(float)left[b], aspf=(float)asp[b], tlf=(float)tl[b];
    float rr=lf+aspf-1.f, ctx=tlf-aspf;
    #pragma unroll
    for(int p=0;p<4;p++){
      float jf = (float)((mtile&1)*128 + a_row + p*32);
      float w;
      if(jf < lf)       w = 1.f-(lf-jf)/ctx;
      else if(jf <= rr) w = 0.f;
      else if(jf < tlf) w = 1.f-(jf-rr)/ctx;
      else              w = 0.f;
      wgt_[p] = w;
    }
  }

  float4 pa[4];
  u32x4 pwh[2], pwl[2];

  #pragma unroll
  for(int p=0;p<4;p++)
    pa[p] = *(const float4*)(A + (size_t)(m0 + a_row + p*32)*ND + a_kq*4);
  #pragma unroll
  for(int h=0;h<2;h++){
    size_t woff = (size_t)(n0 + w_n + h*64)*ND + w_kc*8;
    pwh[h] = *(const u32x4*)(Wth + woff);
    pwl[h] = *(const u32x4*)(Wtl + woff);
  }

  for(int k0=0; k0<ND; k0+=32){
    #pragma unroll
    for(int p=0;p<4;p++){
      int row = a_row + p*32;
      unsigned int h01, l01, h23, l23;
      split2(pa[p].x*wgt_[p], pa[p].y*wgt_[p], h01, l01);
      split2(pa[p].z*wgt_[p], pa[p].w*wgt_[p], h23, l23);
      int off = row*ROWB + a_kq*8;
      *(u32x2*)(Ahi + off) = (u32x2){h01, h23};
      *(u32x2*)(Alo + off) = (u32x2){l01, l23};
    }
    #pragma unroll
    for(int h=0;h<2;h++){
      int off = (w_n + h*64)*ROWB + w_kc*16;
      *(u32x4*)(Bhi + off) = pwh[h];
      *(u32x4*)(Blo + off) = pwl[h];
    }
    __syncthreads();

    if(k0 + 32 < ND){
      int kn = k0 + 32;
      #pragma unroll
      for(int p=0;p<4;p++)
        pa[p] = *(const float4*)(A + (size_t)(m0 + a_row + p*32)*ND + kn + a_kq*4);
      #pragma unroll
      for(int h=0;h<2;h++){
        size_t woff = (size_t)(n0 + w_n + h*64)*ND + kn + w_kc*8;
        pwh[h] = *(const u32x4*)(Wth + woff);
        pwl[h] = *(const u32x4*)(Wtl + woff);
      }
    }

    bf16x8 ah[4], al[4], bh[4], bl[4];
    #pragma unroll
    for(int mi=0;mi<4;mi++){
      int r = wr*64 + mi*16 + lrow;
      int off = r*ROWB + kb*16;
      ah[mi] = *(const bf16x8*)(Ahi + off);
      al[mi] = *(const bf16x8*)(Alo + off);
    }
    #pragma unroll
    for(int ni=0;ni<4;ni++){
      int n = wc*64 + ni*16 + lrow;
      int off = n*ROWB + kb*16;
      bh[ni] = *(const bf16x8*)(Bhi + off);
      bl[ni] = *(const bf16x8*)(Blo + off);
    }

    #pragma unroll
    for(int mi=0;mi<4;mi++)
      #pragma unroll
      for(int ni=0;ni<4;ni++){
        acc[mi][ni] = __builtin_amdgcn_mfma_f32_16x16x32_bf16(ah[mi], bh[ni], acc[mi][ni], 0,0,0);
        acc[mi][ni] = __builtin_amdgcn_mfma_f32_16x16x32_bf16(ah[mi], bl[ni], acc[mi][ni], 0,0,0);
        acc[mi][ni] = __builtin_amdgcn_mfma_f32_16x16x32_bf16(al[mi], bh[ni], acc[mi][ni], 0,0,0);
      }
    __syncthreads();
  }

  int rg = lane >> 4;
  int cc = lane & 15;
  if(MODE == 0){
    #pragma unroll
    for(int mi=0;mi<4;mi++)
      #pragma unroll
      for(int ni=0;ni<4;ni++){
        int col = n0 + wc*64 + ni*16 + cc;
        #pragma unroll
        for(int q=0;q<4;q++){
          int row = m0 + wr*64 + mi*16 + rg*4 + q;
          C[(size_t)row*ND + col] = acc[mi][ni][q];
        }
      }
  } else {
    float S0 = scal[0], S1 = scal[1];
    float* CT = (float*)lds;   // 64*130 floats (fits staging LDS)
    int b = m0 >> 8;
    int ibase = m0 & 255;
    int tr   = t >> 1;
    int tch  = t & 1;
    float tpsum = 0.f;
    #pragma unroll
    for(int p=0;p<2;p++){
      if(wc == p){
        #pragma unroll
        for(int mi=0;mi<4;mi++)
          #pragma unroll
          for(int ni=0;ni<4;ni++)
            #pragma unroll
            for(int q=0;q<4;q++)
              CT[(ni*16+cc)*130 + wr*64 + mi*16 + rg*4 + q] = acc[mi][ni][q];
      }
      __syncthreads();
      // transposed bf16 planes [b][d][i]
      int lcol = t >> 6;
      int lrow2 = (t & 63)*2;
      #pragma unroll
      for(int u=0;u<16;u++){
        int c = lcol + u*4;
        float2 v2 = *(float2*)&CT[c*130 + lrow2];
        unsigned int hi, lo;
        split2(v2.x, v2.y, hi, lo);
        size_t uidx = ((size_t)b*HTB + (size_t)(n0 + p*64 + c)*256 + ibase + lrow2) >> 1;
        hiP[uidx] = hi;
        loP[uidx] = lo;
      }
      // Pscore: pair-reduced scores, rounded bf16, packed into the (b,itile) h1 region
      {
        int cpr = t & 31;
        int rq  = t >> 5;
        #pragma unroll
        for(int rr2=0; rr2<16; rr2++){
          int row = rq*16 + rr2;
          float pval = S0*CT[(2*cpr)*130 + row] + S1*CT[(2*cpr+1)*130 + row];
          int ig = ibase + row;
          unsigned int pb = __float_as_uint(pval);
          ushort_t po = (ushort_t)((pb + 0x7FFFu + ((pb>>16)&1u)) >> 16);
          size_t addr = (size_t)b*262144 + (size_t)(ig>>5)*32768
                      + (size_t)(ig&31)*256 + (n0>>1) + p*32 + cpr;
          Pbuf[addr] = po;
        }
      }
      // t-partial over this 64-d slab
      #pragma unroll 8
      for(int cc2=0; cc2<32; cc2++){
        int c = tch*32 + cc2;
        tpsum = fmaf(CT[c*130 + tr], a2[n0 + p*64 + c], tpsum);
      }
      __syncthreads();
    }
    tpsum += __shfl_xor(tpsum, 1);
    if(tch == 0) tp4[(n0>>7)*32768 + m0 + tr] = tpsum;
  }
}

__global__ __launch_bounds__(256) void k_gemm_t(const float* __restrict__ A,
                                                const ushort_t* __restrict__ Wth,
                                                const ushort_t* __restrict__ Wtl,
                                                unsigned int* __restrict__ hiP,
                                                unsigned int* __restrict__ loP,
                                                ushort_t* __restrict__ Pbuf,
                                                float* __restrict__ tp4,
                                                const float* __restrict__ a2,
                                                const float* __restrict__ scal,
                                                const int* __restrict__ left,
                                                const int* __restrict__ asp,
                                                const int* __restrict__ tl){
  __shared__ unsigned char lds[4*128*ROWB];
  // XCD swizzle: 4 n-tiles of each m-tile within 32 consecutive bids, all same (bid mod 8)
  int bid = blockIdx.x;
  int ntile = (bid >> 3) & 3;
  int mtile = (bid & 7) | ((bid >> 5) << 3);
  gemm_tile<1>(A, Wth, Wtl, nullptr, hiP, loP, Pbuf, tp4, a2, scal, left, asp, tl,
               mtile, ntile, lds);
}

__global__ __launch_bounds__(256) void k_gemm_b(const float* __restrict__ Abase, long aStride,
                                                const ushort_t* __restrict__ Wth,
                                                const ushort_t* __restrict__ Wtl,
                                                float* __restrict__ Cbase){
  __shared__ unsigned char lds[4*128*ROWB];
  int l  = blockIdx.x >> 5;
  int tb = blockIdx.x & 31;
  gemm_tile<0>(Abase + (size_t)l*aStride, Wth + (size_t)l*DD, Wtl + (size_t)l*DD,
               Cbase + (size_t)l*MN, nullptr, nullptr, nullptr, nullptr,
               nullptr, nullptr, nullptr, nullptr, nullptr, tb>>2, tb&3, lds);
}

// layer-0 attention: coalesced bf16-P softmax (lanes=j, adj direct int4)
// + MFMA aggregation (att single-plane bf16) with global_load_lds-staged B planes.
__global__ __launch_bounds__(256) void k_attn0(
    const ushort_t* __restrict__ hTH, const ushort_t* __restrict__ hTL,
    const int* __restrict__ adj,
    const float* __restrict__ tpart,
    const int* __restrict__ left, const int* __restrict__ asp, const int* __restrict__ tl,
    float* __restrict__ PA){
  __shared__ unsigned char attH[32*512];   // bf16 att [32 i][256 j], XOR-swizzled
  __shared__ unsigned char BsH[16384];     // staged hi plane [256 d][32 j] linear 64B rows
  __shared__ unsigned char BsL[16384];

  int bid = blockIdx.x;
  int b  = bid & 127;      // 8 blocks of batch b land on same XCD
  int ic = bid >> 7;
  int i0 = ic*32;
  int tid = threadIdx.x;
  int lane = tid & 63, w = tid >> 6;
  const ushort_t* HH = hTH + (size_t)b*HTB;
  const ushort_t* HL = hTL + (size_t)b*HTB;
  const ushort_t* Pt = (const ushort_t*)PA + (size_t)b*262144 + (size_t)ic*32768;

  // ---- phase 1: softmax, lanes = j (4 j's per lane) ----
  float t0v=0.f, t1v=0.f, t2v=0.f, t3v=0.f;
  #pragma unroll
  for(int nt=0; nt<4; nt++){
    float4 tv = ((const float4*)(tpart + nt*32768 + b*256))[lane];
    t0v += tv.x; t1v += tv.y; t2v += tv.z; t3v += tv.w;
  }

  for(int rr=0; rr<8; rr++){
    int il = w*8 + rr;         // 0..31
    int i  = i0 + il;
    u32x2 pw = *(const u32x2*)(Pt + il*256 + lane*4);
    float pv0 = bfu((ushort_t)(pw[0] & 0xFFFFu));
    float pv1 = bfu((ushort_t)(pw[0] >> 16));
    float pv2 = bfu((ushort_t)(pw[1] & 0xFFFFu));
    float pv3 = bfu((ushort_t)(pw[1] >> 16));
    int4 av = ((const int4*)(adj + ((size_t)b*NLQ + i)*NLQ))[lane];
    float e0 = fmaxf(pv0 + t0v, 0.f);
    float e1 = fmaxf(pv1 + t1v, 0.f);
    float e2 = fmaxf(pv2 + t2v, 0.f);
    float e3 = fmaxf(pv3 + t3v, 0.f);
    float m = -3.0e38f;
    if(av.x>0) m = e0;
    if(av.y>0) m = fmaxf(m, e1);
    if(av.z>0) m = fmaxf(m, e2);
    if(av.w>0) m = fmaxf(m, e3);
    m = wave_max(m);
    float p0 = (av.x>0) ? __expf(e0-m) : 0.f;
    float p1 = (av.y>0) ? __expf(e1-m) : 0.f;
    float p2 = (av.z>0) ? __expf(e2-m) : 0.f;
    float p3 = (av.w>0) ? __expf(e3-m) : 0.f;
    float s = wave_sum(p0+p1+p2+p3);
    float inv = 1.f/s;
    unsigned int w0 = pack2_bf16(p0*inv, p1*inv);
    unsigned int w1 = pack2_bf16(p2*inv, p3*inv);
    int off = il*512 + ((lane*8) ^ ((il&7)<<4));
    *(u32x2*)(attH + off) = (u32x2){w0,w1};
  }

  // ---- phase 2: O[i][d] = att @ h via MFMA; B staged via global_load_lds ----
  int wm = w >> 1, wn = w & 1;
  int lrow = lane & 15, kb = lane >> 4;
  int rg = lane >> 4, cc = lane & 15;
  float lf=(float)left[b], aspf=(float)asp[b], tlf=(float)tl[b];
  float rrv=lf+aspf-1.f, ctx=tlf-aspf;
  int arow = wm*16 + lrow;
  int aswz = (arow&7)<<4;

  for(int dp=0; dp<2; dp++){
    int d0 = dp*256;
    f32x4 acc[8];
    #pragma unroll
    for(int ni=0;ni<8;ni++) acc[ni] = (f32x4){0.f,0.f,0.f,0.f};
    for(int ks=0; ks<8; ks++){
      int j0 = ks*32;
      __syncthreads();   // previous tile fully consumed (also orders att writes)
      #pragma unroll
      for(int u=0;u<4;u++){
        int chunk = (u*4 + w)*64 + lane;
        int row = chunk >> 2, sl = chunk & 3;
        const ushort_t* gph = HH + (size_t)(d0+row)*256 + j0 + sl*8;
        const ushort_t* gpl = HL + (size_t)(d0+row)*256 + j0 + sl*8;
        GLOAD16(gph, BsH + (u*4+w)*1024);
        GLOAD16(gpl, BsL + (u*4+w)*1024);
      }
      __syncthreads();   // loads landed
      int aoff = arow*512 + ((j0*2 + kb*16) ^ aswz);
      bf16x8 ah = *(const bf16x8*)(attH + aoff);
      #pragma unroll
      for(int ni=0; ni<8; ni++){
        int boff = (wn*128 + ni*16 + lrow)*64 + kb*16;
        bf16x8 bh = *(const bf16x8*)(BsH + boff);
        bf16x8 bl = *(const bf16x8*)(BsL + boff);
        acc[ni] = __builtin_amdgcn_mfma_f32_16x16x32_bf16(ah, bh, acc[ni], 0,0,0);
        acc[ni] = __builtin_amdgcn_mfma_f32_16x16x32_bf16(ah, bl, acc[ni], 0,0,0);
      }
    }
    #pragma unroll
    for(int q=0;q<4;q++){
      int row = i0 + wm*16 + rg*4 + q;
      float fi = (float)row;
      float wgt;
      if(fi < lf)        wgt = 1.f-(lf-fi)/ctx;
      else if(fi <= rrv) wgt = 0.f;
      else if(fi < tlf)  wgt = 1.f-(fi-rrv)/ctx;
      else               wgt = 0.f;
      #pragma unroll
      for(int ni=0;ni<8;ni++){
        int col = d0 + wn*128 + ni*16 + cc;
        PA[((size_t)b*NLQ + row)*ND + col] = wgt*fmaxf(acc[ni][q], 0.f);
      }
    }
  }
}

// T[l][b*256+j] = h1[b,j,:] . v_l
__global__ __launch_bounds__(256) void k_tv(const float* __restrict__ h1,
                                            const float* __restrict__ v,
                                            float* __restrict__ T){
  int row  = blockIdx.x*4 + (threadIdx.x>>6);
  int lane = threadIdx.x & 63;
  const float4* hr = (const float4*)(h1 + (size_t)row*ND);
  float4 h0 = hr[lane], h1v = hr[lane+64];
  float s0,s1,s2,s3,s4;
  #define DOTV(SL, L) { \
    const float4* vr = (const float4*)(v + (L)*ND); \
    float4 v0 = vr[lane], v1 = vr[lane+64]; \
    float dd = h0.x*v0.x+h0.y*v0.y+h0.z*v0.z+h0.w*v0.w \
             + h1v.x*v1.x+h1v.y*v1.y+h1v.z*v1.z+h1v.w*v1.w; \
    SL = wave_sum(dd); }
  DOTV(s0,0) DOTV(s1,1) DOTV(s2,2) DOTV(s3,3) DOTV(s4,4)
  #undef DOTV
  if(lane==0){
    T[0*32768 + row]=s0; T[1*32768 + row]=s1; T[2*32768 + row]=s2;
    T[3*32768 + row]=s3; T[4*32768 + row]=s4;
  }
}

__global__ __launch_bounds__(256) void k_rows(const float* __restrict__ h1,
                                              const int* __restrict__ left, const int* __restrict__ asp,
                                              float* __restrict__ R){
  int b = blockIdx.x;
  int nk = asp[b], l0 = left[b];
  const float4* src = (const float4*)(h1 + (size_t)b*NLQ*ND);
  float4* dst = (float4*)(R + (size_t)b*8*ND);
  #pragma unroll
  for(int u=0; u<4; u++){
    int f4 = threadIdx.x + u*256;
    int k = f4 >> 7, c = f4 & 127;
    float4 val = (k<nk) ? src[(size_t)(l0+k)*128 + c] : (float4){0.f,0.f,0.f,0.f};
    dst[f4] = val;
  }
}

// all 25 (layer,row) atts for one batch; y = att @ h1. 2 blocks per b (d halves).
__global__ __launch_bounds__(256) void k_att5(const float* __restrict__ h1,
    const float* __restrict__ Hasp, const float* __restrict__ T,
    const int* __restrict__ adj, const float* __restrict__ scal,
    const int* __restrict__ left, const int* __restrict__ asp,
    float* __restrict__ y){
  __shared__ float att[25][260];
  int b  = blockIdx.x & 127;
  int dh = blockIdx.x >> 7;
  int tid = threadIdx.x, lane = tid&63, w = tid>>6;
  int nk = asp[b], l0 = left[b];

  for(int r = w; r < 25; r += 4){
    int l = r/5, k = r - l*5;
    if(k < nk){
      float S0 = scal[2*(l+1)], S1 = scal[2*(l+1)+1];
      const float2* hrow = (const float2*)(Hasp + (size_t)l*MN + (size_t)(b*8+k)*ND);
      const int* arow = adj + ((size_t)b*NLQ + (l0+k))*NLQ;
      const float* Tl = T + l*32768 + b*256;
      float e[4]; int av[4];
      float m = -3.0e38f;
      #pragma unroll
      for(int q=0;q<4;q++){
        int j = lane + 64*q;
        float2 hp = hrow[j];
        av[q] = arow[j];
        e[q] = fmaxf(S0*hp.x + S1*hp.y + Tl[j], 0.f);
        if(av[q] > 0) m = fmaxf(m, e[q]);
      }
      m = wave_max(m);
      float pp[4]; float s = 0.f;
      #pragma unroll
      for(int q=0;q<4;q++){
        pp[q] = (av[q] > 0) ? __expf(e[q]-m) : 0.f;
        s += pp[q];
      }
      s = wave_sum(s);
      float inv = 1.f/s;
      #pragma unroll
      for(int q=0;q<4;q++) att[r][lane+64*q] = pp[q]*inv;
    } else {
      #pragma unroll
      for(int q=0;q<4;q++) att[r][lane+64*q] = 0.f;
    }
  }
  __syncthreads();

  int d = dh*256 + tid;
  const float* hb = h1 + (size_t)b*NLQ*ND;
  float acc[25];
  #pragma unroll
  for(int r=0;r<25;r++) acc[r]=0.f;
  for(int jj=0; jj<NLQ; jj++){
    float hv = hb[(size_t)jj*ND + d];
    #pragma unroll
    for(int r=0;r<25;r++) acc[r] += att[r][jj]*hv;
  }
  #pragma unroll
  for(int r=0;r<25;r++){
    int l = r/5, k = r - l*5;
    y[(size_t)l*MN + ((size_t)b*8+k)*ND + d] = acc[r];
  }
  #pragma unroll
  for(int l=0;l<5;l++)
    #pragma unroll
    for(int k=5;k<8;k++)
      y[(size_t)l*MN + ((size_t)b*8+k)*ND + d] = 0.f;
}

__global__ __launch_bounds__(256) void k_g(const float* __restrict__ hp,
    const int* __restrict__ asp, float* __restrict__ g){
  int b = blockIdx.x, d = threadIdx.x;
  int nk = asp[b];
  float gx=0.f, gy=0.f;
  for(int l=0;l<5;l++){
    for(int k=0;k<nk;k++){
      const float* r = hp + (size_t)l*MN + (size_t)(b*8+k)*ND;
      gx += fmaxf(r[d], 0.f);
      gy += fmaxf(r[d+256], 0.f);
    }
  }
  g[b*ND + d]       = 0.2f*gx;
  g[b*ND + 256 + d] = 0.2f*gy;
}

__global__ __launch_bounds__(256) void k_dot(const float* __restrict__ x,
    const float* __restrict__ g, float* __restrict__ s){
  int row  = blockIdx.x*4 + (threadIdx.x>>6);
  int b    = row >> 8;
  int lane = threadIdx.x & 63;
  const float4* xr = (const float4*)(x + (size_t)row*ND);
  const float4* gr = (const float4*)(g + (size_t)b*ND);
  float4 x0=xr[lane], x1=xr[lane+64], g0=gr[lane], g1=gr[lane+64];
  float d = x0.x*g0.x + x0.y*g0.y + x0.z*g0.z + x0.w*g0.w
          + x1.x*g1.x + x1.y*g1.y + x1.z*g1.z + x1.w*g1.w;
  d = wave_sum(d);
  if(lane==0) s[row] = d;
}

__global__ __launch_bounds__(256) void k_out(const float* __restrict__ x,
    const float* __restrict__ s, float* __restrict__ out){
  int b  = blockIdx.x >> 2;
  int ch = blockIdx.x & 3;
  int tid = threadIdx.x, lane = tid&63, w = tid>>6;
  __shared__ float red[4];
  __shared__ float alpha[NLQ];
  __shared__ float part[128];
  float sv = s[b*NLQ + tid];
  float m = wave_max(sv);
  if(lane==0) red[w] = m;
  __syncthreads();
  m = fmaxf(fmaxf(red[0],red[1]), fmaxf(red[2],red[3]));
  float p = __expf(sv - m);
  float su = wave_sum(p);
  __syncthreads();
  if(lane==0) red[w] = su;
  __syncthreads();
  su = red[0]+red[1]+red[2]+red[3];
  alpha[tid] = p/su;
  __syncthreads();
  int d = ch*128 + (tid & 127);
  int half = tid >> 7;
  const float* xb = x + (size_t)b*NLQ*ND;
  float acc = 0.f;
  for(int mm = half*128; mm < half*128 + 128; mm++)
    acc += alpha[mm] * xb[(size_t)mm*ND + d];
  if(half) part[tid & 127] = acc;
  __syncthreads();
  if(!half) out[(size_t)b*ND + d] = acc + part[tid & 127];
}

extern "C" void kernel_launch(void* const* d_in, const int* in_sizes, int n_in,
                              void* d_out, int out_size, void* d_ws, size_t ws_size,
                              hipStream_t stream){
  const float* x    = (const float*)d_in[0];
  const float* Wst  = (const float*)d_in[1];
  const float* ast  = (const float*)d_in[2];
  const int*   adj  = (const int*)d_in[3];
  const int*   left = (const int*)d_in[4];
  const int*   asp  = (const int*)d_in[5];
  const int*   tl   = (const int*)d_in[6];
  float* out = (float*)d_out;
  float* ws  = (float*)d_ws;

  const size_t SZ = (size_t)NB*NLQ*ND;
  float* bufA = ws;                     // P (bf16) -> h1 (block-local overwrite)
  float* bufB = ws + SZ;                // bf16 planes; later Hasp/ybuf/hp/R/Wt15
  float* ws2  = ws + 2*SZ;
  float* tpart= ws2;                    // 4*32768
  float* T    = tpart + 4*32768;        // 163840
  float* g    = T + 163840;             // 65536
  float* scal = g + 65536;              // 16
  float* v    = scal + 16;              // 2560
  float* sbuf = v + 2560;               // 32768
  ushort_t* w0th = (ushort_t*)(sbuf + 32768);  // 262144 ushorts (layer-0 Wt hi)
  ushort_t* w0tl = w0th + DD;                  // 262144 ushorts (lo) -- 1 MB total (proven slot)

  ushort_t* hTH = (ushort_t*)bufB;
  ushort_t* hTL = hTH + (size_t)NB*HTB;

  float* Hasp = bufB;                   // reuse after k_attn0
  float* ybuf = Hasp + (size_t)5*MN;
  float* hp   = ybuf + (size_t)5*MN;
  float* R    = hp   + (size_t)5*MN;    // MN floats
  ushort_t* wt15h = (ushort_t*)(R + MN);       // 5*DD ushorts
  ushort_t* wt15l = wt15h + (size_t)5*DD;      // 5*DD ushorts

  k_scal<<<NLAYERS, 256, 0, stream>>>(ast, scal);
  k_wa2<<<5*128, 256, 0, stream>>>(Wst, ast, v);
  k_wsplit<<<64, 256, 0, stream>>>(Wst, w0th, w0tl);

  // layer 0: posw fused in A-stage; emits bf16 planes + bf16 pair-scores P + t-partials
  k_gemm_t<<<(NB*NLQ/128)*(ND/128), 256, 0, stream>>>(x, w0th, w0tl,
      (unsigned int*)hTH, (unsigned int*)hTL, (ushort_t*)bufA, tpart, ast + ND,
      scal, left, asp, tl);
  k_attn0<<<NB*8, 256, 0, stream>>>(hTH, hTL, adj, tpart, left, asp, tl, bufA);

  // layers 1..5 on aspect rows only
  k_wsplit<<<5*64, 256, 0, stream>>>(Wst + DD, wt15h, wt15l);
  k_tv<<<NB*NLQ/4, 256, 0, stream>>>(bufA, v, T);
  k_rows<<<NB, 256, 0, stream>>>(bufA, left, asp, R);
  k_gemm_b<<<5*32, 256, 0, stream>>>(R, 0L, wt15h, wt15l, Hasp);
  k_att5<<<NB*2, 256, 0, stream>>>(bufA, Hasp, T, adj, scal, left, asp, ybuf);
  k_gemm_b<<<5*32, 256, 0, stream>>>(ybuf, (long)MN, wt15h, wt15l, hp);
  k_g<<<NB, 256, 0, stream>>>(hp, asp, g);

  // final attention over original x
  k_dot<<<NB*NLQ/4, 256, 0, stream>>>(x, g, sbuf);
  k_out<<<NB*4, 256, 0, stream>>>(x, sbuf, out);
}

// Round 12
// 253.018 us; speedup vs baseline: 1.3016x; 1.2832x over previous
//
#include <hip/hip_runtime.h>

#define NB 128
#define NLQ 256   // sequence length L
#define ND 512    // feature dim D
#define NLAYERS 6
#define DD (ND*ND)
#define MN (1024*ND)
#define HTB 131072   // fp16 elems per batch in hT plane: 512*256

typedef _Float16 f16x8 __attribute__((ext_vector_type(8)));
typedef __fp16 fp16x2 __attribute__((ext_vector_type(2)));
typedef _Float16 f16x4v __attribute__((ext_vector_type(4)));
typedef float f32x4 __attribute__((ext_vector_type(4)));
typedef unsigned int u32x2 __attribute__((ext_vector_type(2)));
typedef unsigned int u32x4 __attribute__((ext_vector_type(4)));
typedef unsigned short ushort_t;

#define GLOAD16(gp, lp) __builtin_amdgcn_global_load_lds( \
    (const __attribute__((address_space(1))) void*)(gp), \
    (__attribute__((address_space(3))) void*)(lp), 16, 0, 0)

__device__ __forceinline__ float wave_max(float v){
  #pragma unroll
  for(int off=32; off; off>>=1) v = fmaxf(v, __shfl_xor(v, off));
  return v;
}
__device__ __forceinline__ float wave_sum(float v){
  #pragma unroll
  for(int off=32; off; off>>=1) v += __shfl_xor(v, off);
  return v;
}
// pack two fp32 into one dword of fp16 (v_cvt_pkrtz_f16_f32, single instr)
__device__ __forceinline__ unsigned int pk16(float a, float b){
  fp16x2 h = __builtin_amdgcn_cvt_pkrtz(a, b);
  return __builtin_bit_cast(unsigned int, h);
}

__global__ __launch_bounds__(256) void k_scal(const float* __restrict__ a_stack,
                                              float* __restrict__ scal){
  int layer = blockIdx.x;
  const float* a = a_stack + (size_t)layer*2*ND;
  int t = threadIdx.x;
  float v0 = a[t];
  float v1 = a[256 + t];
  v0 = wave_sum(v0); v1 = wave_sum(v1);
  __shared__ float s0[4], s1[4];
  int wave = t>>6, lane = t&63;
  if(lane==0){ s0[wave]=v0; s1[wave]=v1; }
  __syncthreads();
  if(t==0){
    scal[layer*2+0] = s0[0]+s0[1]+s0[2]+s0[3];
    scal[layer*2+1] = s1[0]+s1[1]+s1[2]+s1[3];
  }
}

// v_l[i] = dot(W_{l+1}[i,:], a2_{l+1})
__global__ __launch_bounds__(256) void k_wa2(const float* __restrict__ Wst,
                                             const float* __restrict__ ast,
                                             float* __restrict__ v){
  int l  = blockIdx.x >> 7;
  int rg = blockIdx.x & 127;
  int i  = rg*4 + (threadIdx.x>>6);
  int lane = threadIdx.x & 63;
  const float4* wr = (const float4*)(Wst + (size_t)(l+1)*DD + (size_t)i*ND);
  const float4* ar = (const float4*)(ast + (size_t)(l+1)*2*ND + ND);
  float4 w0=wr[lane], w1=wr[lane+64], a0=ar[lane], a1=ar[lane+64];
  float d = w0.x*a0.x + w0.y*a0.y + w0.z*a0.z + w0.w*a0.w
          + w1.x*a1.x + w1.y*a1.y + w1.z*a1.z + w1.w*a1.w;
  d = wave_sum(d);
  if(lane==0) v[l*ND + i] = d;
}

// transpose + convert W layers to single fp16 plane Wt[n][k]. One 64x64 tile per block.
__global__ __launch_bounds__(256) void k_wcvt(const float* __restrict__ Wsrc,
                                              ushort_t* __restrict__ Ho){
  __shared__ float CT[64][65];
  int bid = blockIdx.x;
  int l  = bid >> 6;
  int kt = (bid >> 3) & 7, nt = bid & 7;
  const float* Wl = Wsrc + (size_t)l*DD;
  int t = threadIdx.x;
  int r = t >> 2, c4 = (t&3)*16;
  #pragma unroll
  for(int u=0;u<4;u++){
    float4 vv = *(const float4*)(Wl + (size_t)(kt*64+r)*ND + nt*64 + c4 + u*4);
    CT[r][c4+u*4+0]=vv.x; CT[r][c4+u*4+1]=vv.y;
    CT[r][c4+u*4+2]=vv.z; CT[r][c4+u*4+3]=vv.w;
  }
  __syncthreads();
  int n = t >> 2, kc = t & 3;
  unsigned int o[8];
  #pragma unroll
  for(int j=0;j<8;j++)
    o[j] = pk16(CT[kc*16 + 2*j][n], CT[kc*16 + 2*j + 1][n]);
  ushort_t* dh = Ho + (size_t)l*DD + (size_t)(nt*64+n)*ND + kt*64 + kc*16;
  *(u32x4*)(dh)     = (u32x4){o[0],o[1],o[2],o[3]};
  *(u32x4*)(dh + 8) = (u32x4){o[4],o[5],o[6],o[7]};
}

// ---- fp16 single-term MFMA GEMM tile: C[128x128] = A[128x512]@W[512x128] ----
// W pre-converted/transposed as fp16 plane Wt[n][k]. A fp32, converted in staging.
// MODE=0: C row-major [M][512].
// MODE=1: posw fused into A-stage; outputs transposed fp16 plane hP[b][d][i],
//         Pscore fp16 (packed per tile), t-partials tp4.
#define ROWB 80
template<int MODE>
__device__ __forceinline__ void gemm_tile(const float* __restrict__ A,
                                          const ushort_t* __restrict__ Wth,
                                          float* __restrict__ C,
                                          unsigned int* __restrict__ hP,
                                          ushort_t* __restrict__ Pbuf,
                                          float* __restrict__ tp4,
                                          const float* __restrict__ a2,
                                          const float* __restrict__ scal,
                                          const int* __restrict__ left,
                                          const int* __restrict__ asp,
                                          const int* __restrict__ tl,
                                          int mtile, int ntile, unsigned char* lds){
  unsigned char* Ah = lds;                 // 128*80
  unsigned char* Bh = lds + 128*ROWB;      // 128*80

  int t = threadIdx.x;
  int m0 = mtile*128, n0 = ntile*128;
  int lane = t & 63, wid = t >> 6;
  int wr = wid >> 1, wc = wid & 1;
  int lrow = lane & 15, kb = lane >> 4;

  f32x4 acc[4][4];
  #pragma unroll
  for(int mi=0;mi<4;mi++)
    #pragma unroll
    for(int ni=0;ni<4;ni++)
      acc[mi][ni] = (f32x4){0.f,0.f,0.f,0.f};

  int a_row = t >> 3;
  int a_kq  = t & 7;
  int w_n   = t >> 2;       // 0..63
  int w_kc  = t & 3;

  float wgt_[4] = {1.f,1.f,1.f,1.f};
  if(MODE == 1){
    int b = mtile >> 1;
    float lf=(float)left[b], aspf=(float)asp[b], tlf=(float)tl[b];
    float rr=lf+aspf-1.f, ctx=tlf-aspf;
    #pragma unroll
    for(int p=0;p<4;p++){
      float jf = (float)((mtile&1)*128 + a_row + p*32);
      float w;
      if(jf < lf)       w = 1.f-(lf-jf)/ctx;
      else if(jf <= rr) w = 0.f;
      else if(jf < tlf) w = 1.f-(jf-rr)/ctx;
      else              w = 0.f;
      wgt_[p] = w;
    }
  }

  float4 pa[4];
  u32x4 pwh[2];

  #pragma unroll
  for(int p=0;p<4;p++)
    pa[p] = *(const float4*)(A + (size_t)(m0 + a_row + p*32)*ND + a_kq*4);
  #pragma unroll
  for(int h=0;h<2;h++)
    pwh[h] = *(const u32x4*)(Wth + (size_t)(n0 + w_n + h*64)*ND + w_kc*8);

  for(int k0=0; k0<ND; k0+=32){
    #pragma unroll
    for(int p=0;p<4;p++){
      int row = a_row + p*32;
      unsigned int c0 = pk16(pa[p].x*wgt_[p], pa[p].y*wgt_[p]);
      unsigned int c1 = pk16(pa[p].z*wgt_[p], pa[p].w*wgt_[p]);
      *(u32x2*)(Ah + row*ROWB + a_kq*8) = (u32x2){c0, c1};
    }
    #pragma unroll
    for(int h=0;h<2;h++)
      *(u32x4*)(Bh + (w_n + h*64)*ROWB + w_kc*16) = pwh[h];
    __syncthreads();

    if(k0 + 32 < ND){
      int kn = k0 + 32;
      #pragma unroll
      for(int p=0;p<4;p++)
        pa[p] = *(const float4*)(A + (size_t)(m0 + a_row + p*32)*ND + kn + a_kq*4);
      #pragma unroll
      for(int h=0;h<2;h++)
        pwh[h] = *(const u32x4*)(Wth + (size_t)(n0 + w_n + h*64)*ND + kn + w_kc*8);
    }

    f16x8 ah[4], bh[4];
    #pragma unroll
    for(int mi=0;mi<4;mi++)
      ah[mi] = *(const f16x8*)(Ah + (wr*64 + mi*16 + lrow)*ROWB + kb*16);
    #pragma unroll
    for(int ni=0;ni<4;ni++)
      bh[ni] = *(const f16x8*)(Bh + (wc*64 + ni*16 + lrow)*ROWB + kb*16);

    #pragma unroll
    for(int mi=0;mi<4;mi++)
      #pragma unroll
      for(int ni=0;ni<4;ni++)
        acc[mi][ni] = __builtin_amdgcn_mfma_f32_16x16x32_f16(ah[mi], bh[ni], acc[mi][ni], 0,0,0);
    __syncthreads();
  }

  int rg = lane >> 4;
  int cc = lane & 15;
  if(MODE == 0){
    #pragma unroll
    for(int mi=0;mi<4;mi++)
      #pragma unroll
      for(int ni=0;ni<4;ni++){
        int col = n0 + wc*64 + ni*16 + cc;
        #pragma unroll
        for(int q=0;q<4;q++){
          int row = m0 + wr*64 + mi*16 + rg*4 + q;
          C[(size_t)row*ND + col] = acc[mi][ni][q];
        }
      }
  } else {
    float S0 = scal[0], S1 = scal[1];
    float* CT = (float*)lds;   // 64*130 floats = 33280 B
    int b = m0 >> 8;
    int ibase = m0 & 255;
    int tr   = t >> 1;
    int tch  = t & 1;
    float tpsum = 0.f;
    #pragma unroll
    for(int p=0;p<2;p++){
      if(wc == p){
        #pragma unroll
        for(int mi=0;mi<4;mi++)
          #pragma unroll
          for(int ni=0;ni<4;ni++)
            #pragma unroll
            for(int q=0;q<4;q++)
              CT[(ni*16+cc)*130 + wr*64 + mi*16 + rg*4 + q] = acc[mi][ni][q];
      }
      __syncthreads();
      // transposed fp16 plane [b][d][i]
      int lcol = t >> 6;
      int lrow2 = (t & 63)*2;
      #pragma unroll
      for(int u=0;u<16;u++){
        int c = lcol + u*4;
        float2 v2 = *(float2*)&CT[c*130 + lrow2];
        size_t uidx = ((size_t)b*HTB + (size_t)(n0 + p*64 + c)*256 + ibase + lrow2) >> 1;
        hP[uidx] = pk16(v2.x, v2.y);
      }
      // Pscore: pair-reduced scores, fp16, packed into the (b,itile) h1 region
      {
        int cpr = t & 31;
        int rq  = t >> 5;
        #pragma unroll
        for(int rr2=0; rr2<16; rr2++){
          int row = rq*16 + rr2;
          float pval = S0*CT[(2*cpr)*130 + row] + S1*CT[(2*cpr+1)*130 + row];
          int ig = ibase + row;
          _Float16 ph = (_Float16)pval;
          size_t addr = (size_t)b*262144 + (size_t)(ig>>5)*32768
                      + (size_t)(ig&31)*256 + (n0>>1) + p*32 + cpr;
          Pbuf[addr] = __builtin_bit_cast(unsigned short, ph);
        }
      }
      // t-partial over this 64-d slab
      #pragma unroll 8
      for(int cc2=0; cc2<32; cc2++){
        int c = tch*32 + cc2;
        tpsum = fmaf(CT[c*130 + tr], a2[n0 + p*64 + c], tpsum);
      }
      __syncthreads();
    }
    tpsum += __shfl_xor(tpsum, 1);
    if(tch == 0) tp4[(n0>>7)*32768 + m0 + tr] = tpsum;
  }
}

__global__ __launch_bounds__(256) void k_gemm_t(const float* __restrict__ A,
                                                const ushort_t* __restrict__ Wth,
                                                unsigned int* __restrict__ hP,
                                                ushort_t* __restrict__ Pbuf,
                                                float* __restrict__ tp4,
                                                const float* __restrict__ a2,
                                                const float* __restrict__ scal,
                                                const int* __restrict__ left,
                                                const int* __restrict__ asp,
                                                const int* __restrict__ tl){
  __shared__ unsigned char lds[33280];   // staging 2*128*80=20480; CT epilogue 33280
  // XCD swizzle: 4 n-tiles of each m-tile within 32 consecutive bids, all same (bid mod 8)
  int bid = blockIdx.x;
  int ntile = (bid >> 3) & 3;
  int mtile = (bid & 7) | ((bid >> 5) << 3);
  gemm_tile<1>(A, Wth, nullptr, hP, Pbuf, tp4, a2, scal, left, asp, tl,
               mtile, ntile, lds);
}

__global__ __launch_bounds__(256) void k_gemm_b(const float* __restrict__ Abase, long aStride,
                                                const ushort_t* __restrict__ Wth,
                                                float* __restrict__ Cbase){
  __shared__ unsigned char lds[2*128*ROWB];
  int l  = blockIdx.x >> 5;
  int tb = blockIdx.x & 31;
  gemm_tile<0>(Abase + (size_t)l*aStride, Wth + (size_t)l*DD,
               Cbase + (size_t)l*MN, nullptr, nullptr, nullptr,
               nullptr, nullptr, nullptr, nullptr, nullptr, tb>>2, tb&3, lds);
}

// layer-0 attention: coalesced fp16-P softmax (lanes=j, adj direct int4)
// + MFMA aggregation (att fp16, h plane fp16, 1 MFMA/frag) with global_load_lds B staging.
__global__ __launch_bounds__(256) void k_attn0(
    const ushort_t* __restrict__ hTH,
    const int* __restrict__ adj,
    const float* __restrict__ tpart,
    const int* __restrict__ left, const int* __restrict__ asp, const int* __restrict__ tl,
    float* __restrict__ PA){
  __shared__ unsigned char attH[32*512];   // fp16 att [32 i][256 j], XOR-swizzled
  __shared__ unsigned char BsH[16384];     // staged fp16 plane [256 d][32 j] linear 64B rows

  int bid = blockIdx.x;
  int b  = bid & 127;      // 8 blocks of batch b land on same XCD
  int ic = bid >> 7;
  int i0 = ic*32;
  int tid = threadIdx.x;
  int lane = tid & 63, w = tid >> 6;
  const ushort_t* HH = hTH + (size_t)b*HTB;
  const ushort_t* Pt = (const ushort_t*)PA + (size_t)b*262144 + (size_t)ic*32768;

  // ---- phase 1: softmax, lanes = j (4 j's per lane) ----
  float t0v=0.f, t1v=0.f, t2v=0.f, t3v=0.f;
  #pragma unroll
  for(int nt=0; nt<4; nt++){
    float4 tv = ((const float4*)(tpart + nt*32768 + b*256))[lane];
    t0v += tv.x; t1v += tv.y; t2v += tv.z; t3v += tv.w;
  }

  for(int rr=0; rr<8; rr++){
    int il = w*8 + rr;         // 0..31
    int i  = i0 + il;
    f16x4v pv = *(const f16x4v*)(Pt + il*256 + lane*4);
    int4 av = ((const int4*)(adj + ((size_t)b*NLQ + i)*NLQ))[lane];
    float e0 = fmaxf((float)pv[0] + t0v, 0.f);
    float e1 = fmaxf((float)pv[1] + t1v, 0.f);
    float e2 = fmaxf((float)pv[2] + t2v, 0.f);
    float e3 = fmaxf((float)pv[3] + t3v, 0.f);
    float m = -3.0e38f;
    if(av.x>0) m = e0;
    if(av.y>0) m = fmaxf(m, e1);
    if(av.z>0) m = fmaxf(m, e2);
    if(av.w>0) m = fmaxf(m, e3);
    m = wave_max(m);
    float p0 = (av.x>0) ? __expf(e0-m) : 0.f;
    float p1 = (av.y>0) ? __expf(e1-m) : 0.f;
    float p2 = (av.z>0) ? __expf(e2-m) : 0.f;
    float p3 = (av.w>0) ? __expf(e3-m) : 0.f;
    float s = wave_sum(p0+p1+p2+p3);
    float inv = 1.f/s;
    unsigned int w0 = pk16(p0*inv, p1*inv);
    unsigned int w1 = pk16(p2*inv, p3*inv);
    int off = il*512 + ((lane*8) ^ ((il&7)<<4));
    *(u32x2*)(attH + off) = (u32x2){w0,w1};
  }

  // ---- phase 2: O[i][d] = att @ h via MFMA; B staged via global_load_lds ----
  int wm = w >> 1, wn = w & 1;
  int lrow = lane & 15, kb = lane >> 4;
  int rg = lane >> 4, cc = lane & 15;
  float lf=(float)left[b], aspf=(float)asp[b], tlf=(float)tl[b];
  float rrv=lf+aspf-1.f, ctx=tlf-aspf;
  int arow = wm*16 + lrow;
  int aswz = (arow&7)<<4;

  for(int dp=0; dp<2; dp++){
    int d0 = dp*256;
    f32x4 acc[8];
    #pragma unroll
    for(int ni=0;ni<8;ni++) acc[ni] = (f32x4){0.f,0.f,0.f,0.f};
    for(int ks=0; ks<8; ks++){
      int j0 = ks*32;
      __syncthreads();   // previous tile fully consumed (also orders att writes)
      #pragma unroll
      for(int u=0;u<4;u++){
        int chunk = (u*4 + w)*64 + lane;
        int row = chunk >> 2, sl = chunk & 3;
        GLOAD16(HH + (size_t)(d0+row)*256 + j0 + sl*8, BsH + (u*4+w)*1024);
      }
      __syncthreads();   // loads landed
      int aoff = arow*512 + ((j0*2 + kb*16) ^ aswz);
      f16x8 ah = *(const f16x8*)(attH + aoff);
      #pragma unroll
      for(int ni=0; ni<8; ni++){
        f16x8 bh = *(const f16x8*)(BsH + (wn*128 + ni*16 + lrow)*64 + kb*16);
        acc[ni] = __builtin_amdgcn_mfma_f32_16x16x32_f16(ah, bh, acc[ni], 0,0,0);
      }
    }
    #pragma unroll
    for(int q=0;q<4;q++){
      int row = i0 + wm*16 + rg*4 + q;
      float fi = (float)row;
      float wgt;
      if(fi < lf)        wgt = 1.f-(lf-fi)/ctx;
      else if(fi <= rrv) wgt = 0.f;
      else if(fi < tlf)  wgt = 1.f-(fi-rrv)/ctx;
      else               wgt = 0.f;
      #pragma unroll
      for(int ni=0;ni<8;ni++){
        int col = d0 + wn*128 + ni*16 + cc;
        PA[((size_t)b*NLQ + row)*ND + col] = wgt*fmaxf(acc[ni][q], 0.f);
      }
    }
  }
}

// T[l][b*256+j] = h1[b,j,:] . v_l
__global__ __launch_bounds__(256) void k_tv(const float* __restrict__ h1,
                                            const float* __restrict__ v,
                                            float* __restrict__ T){
  int row  = blockIdx.x*4 + (threadIdx.x>>6);
  int lane = threadIdx.x & 63;
  const float4* hr = (const float4*)(h1 + (size_t)row*ND);
  float4 h0 = hr[lane], h1v = hr[lane+64];
  float s0,s1,s2,s3,s4;
  #define DOTV(SL, L) { \
    const float4* vr = (const float4*)(v + (L)*ND); \
    float4 v0 = vr[lane], v1 = vr[lane+64]; \
    float dd = h0.x*v0.x+h0.y*v0.y+h0.z*v0.z+h0.w*v0.w \
             + h1v.x*v1.x+h1v.y*v1.y+h1v.z*v1.z+h1v.w*v1.w; \
    SL = wave_sum(dd); }
  DOTV(s0,0) DOTV(s1,1) DOTV(s2,2) DOTV(s3,3) DOTV(s4,4)
  #undef DOTV
  if(lane==0){
    T[0*32768 + row]=s0; T[1*32768 + row]=s1; T[2*32768 + row]=s2;
    T[3*32768 + row]=s3; T[4*32768 + row]=s4;
  }
}

__global__ __launch_bounds__(256) void k_rows(const float* __restrict__ h1,
                                              const int* __restrict__ left, const int* __restrict__ asp,
                                              float* __restrict__ R){
  int b = blockIdx.x;
  int nk = asp[b], l0 = left[b];
  const float4* src = (const float4*)(h1 + (size_t)b*NLQ*ND);
  float4* dst = (float4*)(R + (size_t)b*8*ND);
  #pragma unroll
  for(int u=0; u<4; u++){
    int f4 = threadIdx.x + u*256;
    int k = f4 >> 7, c = f4 & 127;
    float4 val = (k<nk) ? src[(size_t)(l0+k)*128 + c] : (float4){0.f,0.f,0.f,0.f};
    dst[f4] = val;
  }
}

// all 25 (layer,row) atts for one batch; y = att @ h1. 2 blocks per b (d halves).
__global__ __launch_bounds__(256) void k_att5(const float* __restrict__ h1,
    const float* __restrict__ Hasp, const float* __restrict__ T,
    const int* __restrict__ adj, const float* __restrict__ scal,
    const int* __restrict__ left, const int* __restrict__ asp,
    float* __restrict__ y){
  __shared__ float att[25][260];
  int b  = blockIdx.x & 127;
  int dh = blockIdx.x >> 7;
  int tid = threadIdx.x, lane = tid&63, w = tid>>6;
  int nk = asp[b], l0 = left[b];

  for(int r = w; r < 25; r += 4){
    int l = r/5, k = r - l*5;
    if(k < nk){
      float S0 = scal[2*(l+1)], S1 = scal[2*(l+1)+1];
      const float2* hrow = (const float2*)(Hasp + (size_t)l*MN + (size_t)(b*8+k)*ND);
      const int* arow = adj + ((size_t)b*NLQ + (l0+k))*NLQ;
      const float* Tl = T + l*32768 + b*256;
      float e[4]; int av[4];
      float m = -3.0e38f;
      #pragma unroll
      for(int q=0;q<4;q++){
        int j = lane + 64*q;
        float2 hp = hrow[j];
        av[q] = arow[j];
        e[q] = fmaxf(S0*hp.x + S1*hp.y + Tl[j], 0.f);
        if(av[q] > 0) m = fmaxf(m, e[q]);
      }
      m = wave_max(m);
      float pp[4]; float s = 0.f;
      #pragma unroll
      for(int q=0;q<4;q++){
        pp[q] = (av[q] > 0) ? __expf(e[q]-m) : 0.f;
        s += pp[q];
      }
      s = wave_sum(s);
      float inv = 1.f/s;
      #pragma unroll
      for(int q=0;q<4;q++) att[r][lane+64*q] = pp[q]*inv;
    } else {
      #pragma unroll
      for(int q=0;q<4;q++) att[r][lane+64*q] = 0.f;
    }
  }
  __syncthreads();

  int d = dh*256 + tid;
  const float* hb = h1 + (size_t)b*NLQ*ND;
  float acc[25];
  #pragma unroll
  for(int r=0;r<25;r++) acc[r]=0.f;
  for(int jj=0; jj<NLQ; jj++){
    float hv = hb[(size_t)jj*ND + d];
    #pragma unroll
    for(int r=0;r<25;r++) acc[r] += att[r][jj]*hv;
  }
  #pragma unroll
  for(int r=0;r<25;r++){
    int l = r/5, k = r - l*5;
    y[(size_t)l*MN + ((size_t)b*8+k)*ND + d] = acc[r];
  }
  #pragma unroll
  for(int l=0;l<5;l++)
    #pragma unroll
    for(int k=5;k<8;k++)
      y[(size_t)l*MN + ((size_t)b*8+k)*ND + d] = 0.f;
}

__global__ __launch_bounds__(256) void k_g(const float* __restrict__ hp,
    const int* __restrict__ asp, float* __restrict__ g){
  int b = blockIdx.x, d = threadIdx.x;
  int nk = asp[b];
  float gx=0.f, gy=0.f;
  for(int l=0;l<5;l++){
    for(int k=0;k<nk;k++){
      const float* r = hp + (size_t)l*MN + (size_t)(b*8+k)*ND;
      gx += fmaxf(r[d], 0.f);
      gy += fmaxf(r[d+256], 0.f);
    }
  }
  g[b*ND + d]       = 0.2f*gx;
  g[b*ND + 256 + d] = 0.2f*gy;
}

__global__ __launch_bounds__(256) void k_dot(const float* __restrict__ x,
    const float* __restrict__ g, float* __restrict__ s){
  int row  = blockIdx.x*4 + (threadIdx.x>>6);
  int b    = row >> 8;
  int lane = threadIdx.x & 63;
  const float4* xr = (const float4*)(x + (size_t)row*ND);
  const float4* gr = (const float4*)(g + (size_t)b*ND);
  float4 x0=xr[lane], x1=xr[lane+64], g0=gr[lane], g1=gr[lane+64];
  float d = x0.x*g0.x + x0.y*g0.y + x0.z*g0.z + x0.w*g0.w
          + x1.x*g1.x + x1.y*g1.y + x1.z*g1.z + x1.w*g1.w;
  d = wave_sum(d);
  if(lane==0) s[row] = d;
}

__global__ __launch_bounds__(256) void k_out(const float* __restrict__ x,
    const float* __restrict__ s, float* __restrict__ out){
  int b  = blockIdx.x >> 2;
  int ch = blockIdx.x & 3;
  int tid = threadIdx.x, lane = tid&63, w = tid>>6;
  __shared__ float red[4];
  __shared__ float alpha[NLQ];
  __shared__ float part[128];
  float sv = s[b*NLQ + tid];
  float m = wave_max(sv);
  if(lane==0) red[w] = m;
  __syncthreads();
  m = fmaxf(fmaxf(red[0],red[1]), fmaxf(red[2],red[3]));
  float p = __expf(sv - m);
  float su = wave_sum(p);
  __syncthreads();
  if(lane==0) red[w] = su;
  __syncthreads();
  su = red[0]+red[1]+red[2]+red[3];
  alpha[tid] = p/su;
  __syncthreads();
  int d = ch*128 + (tid & 127);
  int half = tid >> 7;
  const float* xb = x + (size_t)b*NLQ*ND;
  float acc = 0.f;
  for(int mm = half*128; mm < half*128 + 128; mm++)
    acc += alpha[mm] * xb[(size_t)mm*ND + d];
  if(half) part[tid & 127] = acc;
  __syncthreads();
  if(!half) out[(size_t)b*ND + d] = acc + part[tid & 127];
}

extern "C" void kernel_launch(void* const* d_in, const int* in_sizes, int n_in,
                              void* d_out, int out_size, void* d_ws, size_t ws_size,
                              hipStream_t stream){
  const float* x    = (const float*)d_in[0];
  const float* Wst  = (const float*)d_in[1];
  const float* ast  = (const float*)d_in[2];
  const int*   adj  = (const int*)d_in[3];
  const int*   left = (const int*)d_in[4];
  const int*   asp  = (const int*)d_in[5];
  const int*   tl   = (const int*)d_in[6];
  float* out = (float*)d_out;
  float* ws  = (float*)d_ws;

  const size_t SZ = (size_t)NB*NLQ*ND;
  float* bufA = ws;                     // P (fp16, packed per tile) -> h1 (block-local overwrite)
  float* bufB = ws + SZ;                // fp16 hT plane; later Hasp/ybuf/hp/R/Wt15
  float* ws2  = ws + 2*SZ;
  float* tpart= ws2;                    // 4*32768
  float* T    = tpart + 4*32768;        // 163840
  float* g    = T + 163840;             // 65536
  float* scal = g + 65536;              // 16
  float* v    = scal + 16;              // 2560
  float* sbuf = v + 2560;               // 32768
  ushort_t* w0th = (ushort_t*)(sbuf + 32768);  // DD ushorts (layer-0 Wt fp16) in proven 1MB slot

  ushort_t* hTH = (ushort_t*)bufB;             // NB*HTB fp16

  float* Hasp = bufB;                   // reuse after k_attn0
  float* ybuf = Hasp + (size_t)5*MN;
  float* hp   = ybuf + (size_t)5*MN;
  float* R    = hp   + (size_t)5*MN;    // MN floats
  ushort_t* wt15h = (ushort_t*)(R + MN);       // 5*DD ushorts

  k_scal<<<NLAYERS, 256, 0, stream>>>(ast, scal);
  k_wa2<<<5*128, 256, 0, stream>>>(Wst, ast, v);
  k_wcvt<<<64, 256, 0, stream>>>(Wst, w0th);

  // layer 0: posw fused in A-stage; emits fp16 plane + fp16 pair-scores P + t-partials
  k_gemm_t<<<(NB*NLQ/128)*(ND/128), 256, 0, stream>>>(x, w0th,
      (unsigned int*)hTH, (ushort_t*)bufA, tpart, ast + ND, scal, left, asp, tl);
  k_attn0<<<NB*8, 256, 0, stream>>>(hTH, adj, tpart, left, asp, tl, bufA);

  // layers 1..5 on aspect rows only
  k_wcvt<<<5*64, 256, 0, stream>>>(Wst + DD, wt15h);
  k_tv<<<NB*NLQ/4, 256, 0, stream>>>(bufA, v, T);
  k_rows<<<NB, 256, 0, stream>>>(bufA, left, asp, R);
  k_gemm_b<<<5*32, 256, 0, stream>>>(R, 0L, wt15h, Hasp);
  k_att5<<<NB*2, 256, 0, stream>>>(bufA, Hasp, T, adj, scal, left, asp, ybuf);
  k_gemm_b<<<5*32, 256, 0, stream>>>(ybuf, (long)MN, wt15h, hp);
  k_g<<<NB, 256, 0, stream>>>(hp, asp, g);

  // final attention over original x
  k_dot<<<NB*NLQ/4, 256, 0, stream>>>(x, g, sbuf);
  k_out<<<NB*4, 256, 0, stream>>>(x, sbuf, out);
}

// Round 13
// 215.390 us; speedup vs baseline: 1.5289x; 1.1747x over previous
//
#include <hip/hip_runtime.h>

#define NB 128
#define NLQ 256   // sequence length L
#define ND 512    // feature dim D
#define NLAYERS 6
#define DD (ND*ND)
#define MN (1024*ND)
#define HTB 131072   // fp16 elems per batch in hT plane: 512*256

typedef _Float16 f16x8 __attribute__((ext_vector_type(8)));
typedef __fp16 fp16x2 __attribute__((ext_vector_type(2)));
typedef _Float16 f16x4v __attribute__((ext_vector_type(4)));
typedef float f32x4 __attribute__((ext_vector_type(4)));
typedef unsigned int u32x2 __attribute__((ext_vector_type(2)));
typedef unsigned int u32x4 __attribute__((ext_vector_type(4)));
typedef unsigned short ushort_t;

#define GLOAD16(gp, lp) __builtin_amdgcn_global_load_lds( \
    (const __attribute__((address_space(1))) void*)(gp), \
    (__attribute__((address_space(3))) void*)(lp), 16, 0, 0)

__device__ __forceinline__ float wave_max(float v){
  #pragma unroll
  for(int off=32; off; off>>=1) v = fmaxf(v, __shfl_xor(v, off));
  return v;
}
__device__ __forceinline__ float wave_sum(float v){
  #pragma unroll
  for(int off=32; off; off>>=1) v += __shfl_xor(v, off);
  return v;
}
// pack two fp32 into one dword of fp16 (v_cvt_pkrtz_f16_f32, single instr)
__device__ __forceinline__ unsigned int pk16(float a, float b){
  fp16x2 h = __builtin_amdgcn_cvt_pkrtz(a, b);
  return __builtin_bit_cast(unsigned int, h);
}

__global__ __launch_bounds__(256) void k_scal(const float* __restrict__ a_stack,
                                              float* __restrict__ scal){
  int layer = blockIdx.x;
  const float* a = a_stack + (size_t)layer*2*ND;
  int t = threadIdx.x;
  float v0 = a[t];
  float v1 = a[256 + t];
  v0 = wave_sum(v0); v1 = wave_sum(v1);
  __shared__ float s0[4], s1[4];
  int wave = t>>6, lane = t&63;
  if(lane==0){ s0[wave]=v0; s1[wave]=v1; }
  __syncthreads();
  if(t==0){
    scal[layer*2+0] = s0[0]+s0[1]+s0[2]+s0[3];
    scal[layer*2+1] = s1[0]+s1[1]+s1[2]+s1[3];
  }
}

// v_l[i] = dot(W_{l+1}[i,:], a2_{l+1})
__global__ __launch_bounds__(256) void k_wa2(const float* __restrict__ Wst,
                                             const float* __restrict__ ast,
                                             float* __restrict__ v){
  int l  = blockIdx.x >> 7;
  int rg = blockIdx.x & 127;
  int i  = rg*4 + (threadIdx.x>>6);
  int lane = threadIdx.x & 63;
  const float4* wr = (const float4*)(Wst + (size_t)(l+1)*DD + (size_t)i*ND);
  const float4* ar = (const float4*)(ast + (size_t)(l+1)*2*ND + ND);
  float4 w0=wr[lane], w1=wr[lane+64], a0=ar[lane], a1=ar[lane+64];
  float d = w0.x*a0.x + w0.y*a0.y + w0.z*a0.z + w0.w*a0.w
          + w1.x*a1.x + w1.y*a1.y + w1.z*a1.z + w1.w*a1.w;
  d = wave_sum(d);
  if(lane==0) v[l*ND + i] = d;
}

// transpose + convert W layers to single fp16 plane Wt[n][k]. One 64x64 tile per block.
__global__ __launch_bounds__(256) void k_wcvt(const float* __restrict__ Wsrc,
                                              ushort_t* __restrict__ Ho){
  __shared__ float CT[64][65];
  int bid = blockIdx.x;
  int l  = bid >> 6;
  int kt = (bid >> 3) & 7, nt = bid & 7;
  const float* Wl = Wsrc + (size_t)l*DD;
  int t = threadIdx.x;
  int r = t >> 2, c4 = (t&3)*16;
  #pragma unroll
  for(int u=0;u<4;u++){
    float4 vv = *(const float4*)(Wl + (size_t)(kt*64+r)*ND + nt*64 + c4 + u*4);
    CT[r][c4+u*4+0]=vv.x; CT[r][c4+u*4+1]=vv.y;
    CT[r][c4+u*4+2]=vv.z; CT[r][c4+u*4+3]=vv.w;
  }
  __syncthreads();
  int n = t >> 2, kc = t & 3;
  unsigned int o[8];
  #pragma unroll
  for(int j=0;j<8;j++)
    o[j] = pk16(CT[kc*16 + 2*j][n], CT[kc*16 + 2*j + 1][n]);
  ushort_t* dh = Ho + (size_t)l*DD + (size_t)(nt*64+n)*ND + kt*64 + kc*16;
  *(u32x4*)(dh)     = (u32x4){o[0],o[1],o[2],o[3]};
  *(u32x4*)(dh + 8) = (u32x4){o[4],o[5],o[6],o[7]};
}

// ---- fp16 single-term MFMA GEMM tile: C[128x128] = A[128x512]@W[512x128] ----
// W pre-converted/transposed as fp16 plane Wt[n][k]. A fp32, converted in staging.
// MODE=0: C row-major [M][512].
// MODE=1: posw fused into A-stage; outputs transposed fp16 plane hP[b][d][i],
//         Pscore fp16 (packed per tile), t-partials tp4.
#define ROWB 80
template<int MODE>
__device__ __forceinline__ void gemm_tile(const float* __restrict__ A,
                                          const ushort_t* __restrict__ Wth,
                                          float* __restrict__ C,
                                          unsigned int* __restrict__ hP,
                                          ushort_t* __restrict__ Pbuf,
                                          float* __restrict__ tp4,
                                          const float* __restrict__ a2,
                                          const float* __restrict__ scal,
                                          const int* __restrict__ left,
                                          const int* __restrict__ asp,
                                          const int* __restrict__ tl,
                                          int mtile, int ntile, unsigned char* lds){
  unsigned char* Ah = lds;                 // 128*80
  unsigned char* Bh = lds + 128*ROWB;      // 128*80

  int t = threadIdx.x;
  int m0 = mtile*128, n0 = ntile*128;
  int lane = t & 63, wid = t >> 6;
  int wr = wid >> 1, wc = wid & 1;
  int lrow = lane & 15, kb = lane >> 4;

  f32x4 acc[4][4];
  #pragma unroll
  for(int mi=0;mi<4;mi++)
    #pragma unroll
    for(int ni=0;ni<4;ni++)
      acc[mi][ni] = (f32x4){0.f,0.f,0.f,0.f};

  int a_row = t >> 3;
  int a_kq  = t & 7;
  int w_n   = t >> 2;       // 0..63
  int w_kc  = t & 3;

  float wgt_[4] = {1.f,1.f,1.f,1.f};
  if(MODE == 1){
    int b = mtile >> 1;
    float lf=(float)left[b], aspf=(float)asp[b], tlf=(float)tl[b];
    float rr=lf+aspf-1.f, ctx=tlf-aspf;
    #pragma unroll
    for(int p=0;p<4;p++){
      float jf = (float)((mtile&1)*128 + a_row + p*32);
      float w;
      if(jf < lf)       w = 1.f-(lf-jf)/ctx;
      else if(jf <= rr) w = 0.f;
      else if(jf < tlf) w = 1.f-(jf-rr)/ctx;
      else              w = 0.f;
      wgt_[p] = w;
    }
  }

  float4 pa[4];
  u32x4 pwh[2];

  #pragma unroll
  for(int p=0;p<4;p++)
    pa[p] = *(const float4*)(A + (size_t)(m0 + a_row + p*32)*ND + a_kq*4);
  #pragma unroll
  for(int h=0;h<2;h++)
    pwh[h] = *(const u32x4*)(Wth + (size_t)(n0 + w_n + h*64)*ND + w_kc*8);

  for(int k0=0; k0<ND; k0+=32){
    #pragma unroll
    for(int p=0;p<4;p++){
      int row = a_row + p*32;
      unsigned int c0 = pk16(pa[p].x*wgt_[p], pa[p].y*wgt_[p]);
      unsigned int c1 = pk16(pa[p].z*wgt_[p], pa[p].w*wgt_[p]);
      *(u32x2*)(Ah + row*ROWB + a_kq*8) = (u32x2){c0, c1};
    }
    #pragma unroll
    for(int h=0;h<2;h++)
      *(u32x4*)(Bh + (w_n + h*64)*ROWB + w_kc*16) = pwh[h];
    __syncthreads();

    if(k0 + 32 < ND){
      int kn = k0 + 32;
      #pragma unroll
      for(int p=0;p<4;p++)
        pa[p] = *(const float4*)(A + (size_t)(m0 + a_row + p*32)*ND + kn + a_kq*4);
      #pragma unroll
      for(int h=0;h<2;h++)
        pwh[h] = *(const u32x4*)(Wth + (size_t)(n0 + w_n + h*64)*ND + kn + w_kc*8);
    }

    f16x8 ah[4], bh[4];
    #pragma unroll
    for(int mi=0;mi<4;mi++)
      ah[mi] = *(const f16x8*)(Ah + (wr*64 + mi*16 + lrow)*ROWB + kb*16);
    #pragma unroll
    for(int ni=0;ni<4;ni++)
      bh[ni] = *(const f16x8*)(Bh + (wc*64 + ni*16 + lrow)*ROWB + kb*16);

    #pragma unroll
    for(int mi=0;mi<4;mi++)
      #pragma unroll
      for(int ni=0;ni<4;ni++)
        acc[mi][ni] = __builtin_amdgcn_mfma_f32_16x16x32_f16(ah[mi], bh[ni], acc[mi][ni], 0,0,0);
    __syncthreads();
  }

  int rg = lane >> 4;
  int cc = lane & 15;
  if(MODE == 0){
    #pragma unroll
    for(int mi=0;mi<4;mi++)
      #pragma unroll
      for(int ni=0;ni<4;ni++){
        int col = n0 + wc*64 + ni*16 + cc;
        #pragma unroll
        for(int q=0;q<4;q++){
          int row = m0 + wr*64 + mi*16 + rg*4 + q;
          C[(size_t)row*ND + col] = acc[mi][ni][q];
        }
      }
  } else {
    float S0 = scal[0], S1 = scal[1];
    float* CT = (float*)lds;   // 64*130 floats = 33280 B
    int b = m0 >> 8;
    int ibase = m0 & 255;
    int tr   = t >> 1;
    int tch  = t & 1;
    float tpsum = 0.f;
    #pragma unroll
    for(int p=0;p<2;p++){
      if(wc == p){
        #pragma unroll
        for(int mi=0;mi<4;mi++)
          #pragma unroll
          for(int ni=0;ni<4;ni++)
            #pragma unroll
            for(int q=0;q<4;q++)
              CT[(ni*16+cc)*130 + wr*64 + mi*16 + rg*4 + q] = acc[mi][ni][q];
      }
      __syncthreads();
      // transposed fp16 plane [b][d][i]
      int lcol = t >> 6;
      int lrow2 = (t & 63)*2;
      #pragma unroll
      for(int u=0;u<16;u++){
        int c = lcol + u*4;
        float2 v2 = *(float2*)&CT[c*130 + lrow2];
        size_t uidx = ((size_t)b*HTB + (size_t)(n0 + p*64 + c)*256 + ibase + lrow2) >> 1;
        hP[uidx] = pk16(v2.x, v2.y);
      }
      // Pscore: pair-reduced scores, fp16, packed into the (b,itile) h1 region
      {
        int cpr = t & 31;
        int rq  = t >> 5;
        #pragma unroll
        for(int rr2=0; rr2<16; rr2++){
          int row = rq*16 + rr2;
          float pval = S0*CT[(2*cpr)*130 + row] + S1*CT[(2*cpr+1)*130 + row];
          int ig = ibase + row;
          _Float16 ph = (_Float16)pval;
          size_t addr = (size_t)b*262144 + (size_t)(ig>>5)*32768
                      + (size_t)(ig&31)*256 + (n0>>1) + p*32 + cpr;
          Pbuf[addr] = __builtin_bit_cast(unsigned short, ph);
        }
      }
      // t-partial over this 64-d slab
      #pragma unroll 8
      for(int cc2=0; cc2<32; cc2++){
        int c = tch*32 + cc2;
        tpsum = fmaf(CT[c*130 + tr], a2[n0 + p*64 + c], tpsum);
      }
      __syncthreads();
    }
    tpsum += __shfl_xor(tpsum, 1);
    if(tch == 0) tp4[(n0>>7)*32768 + m0 + tr] = tpsum;
  }
}

__global__ __launch_bounds__(256) void k_gemm_t(const float* __restrict__ A,
                                                const ushort_t* __restrict__ Wth,
                                                unsigned int* __restrict__ hP,
                                                ushort_t* __restrict__ Pbuf,
                                                float* __restrict__ tp4,
                                                const float* __restrict__ a2,
                                                const float* __restrict__ scal,
                                                const int* __restrict__ left,
                                                const int* __restrict__ asp,
                                                const int* __restrict__ tl){
  __shared__ unsigned char lds[33280];   // staging 2*128*80=20480; CT epilogue 33280
  // XCD swizzle: 4 n-tiles of each m-tile within 32 consecutive bids, all same (bid mod 8)
  int bid = blockIdx.x;
  int ntile = (bid >> 3) & 3;
  int mtile = (bid & 7) | ((bid >> 5) << 3);
  gemm_tile<1>(A, Wth, nullptr, hP, Pbuf, tp4, a2, scal, left, asp, tl,
               mtile, ntile, lds);
}

__global__ __launch_bounds__(256) void k_gemm_b(const float* __restrict__ Abase, long aStride,
                                                const ushort_t* __restrict__ Wth,
                                                float* __restrict__ Cbase){
  __shared__ unsigned char lds[2*128*ROWB];
  int l  = blockIdx.x >> 5;
  int tb = blockIdx.x & 31;
  gemm_tile<0>(Abase + (size_t)l*aStride, Wth + (size_t)l*DD,
               Cbase + (size_t)l*MN, nullptr, nullptr, nullptr,
               nullptr, nullptr, nullptr, nullptr, nullptr, tb>>2, tb&3, lds);
}

// layer-0 attention: coalesced fp16-P softmax (lanes=j, adj direct int4)
// + MFMA aggregation (att fp16, h plane fp16, 1 MFMA/frag) with global_load_lds B staging.
__global__ __launch_bounds__(256) void k_attn0(
    const ushort_t* __restrict__ hTH,
    const int* __restrict__ adj,
    const float* __restrict__ tpart,
    const int* __restrict__ left, const int* __restrict__ asp, const int* __restrict__ tl,
    float* __restrict__ PA){
  __shared__ unsigned char attH[32*512];   // fp16 att [32 i][256 j], XOR-swizzled
  __shared__ unsigned char BsH[16384];     // staged fp16 plane [256 d][32 j] linear 64B rows

  int bid = blockIdx.x;
  int b  = bid & 127;      // 8 blocks of batch b land on same XCD
  int ic = bid >> 7;
  int i0 = ic*32;
  int tid = threadIdx.x;
  int lane = tid & 63, w = tid >> 6;
  const ushort_t* HH = hTH + (size_t)b*HTB;
  const ushort_t* Pt = (const ushort_t*)PA + (size_t)b*262144 + (size_t)ic*32768;

  // ---- phase 1: softmax, lanes = j (4 j's per lane) ----
  float t0v=0.f, t1v=0.f, t2v=0.f, t3v=0.f;
  #pragma unroll
  for(int nt=0; nt<4; nt++){
    float4 tv = ((const float4*)(tpart + nt*32768 + b*256))[lane];
    t0v += tv.x; t1v += tv.y; t2v += tv.z; t3v += tv.w;
  }

  for(int rr=0; rr<8; rr++){
    int il = w*8 + rr;         // 0..31
    int i  = i0 + il;
    f16x4v pv = *(const f16x4v*)(Pt + il*256 + lane*4);
    int4 av = ((const int4*)(adj + ((size_t)b*NLQ + i)*NLQ))[lane];
    float e0 = fmaxf((float)pv[0] + t0v, 0.f);
    float e1 = fmaxf((float)pv[1] + t1v, 0.f);
    float e2 = fmaxf((float)pv[2] + t2v, 0.f);
    float e3 = fmaxf((float)pv[3] + t3v, 0.f);
    float m = -3.0e38f;
    if(av.x>0) m = e0;
    if(av.y>0) m = fmaxf(m, e1);
    if(av.z>0) m = fmaxf(m, e2);
    if(av.w>0) m = fmaxf(m, e3);
    m = wave_max(m);
    float p0 = (av.x>0) ? __expf(e0-m) : 0.f;
    float p1 = (av.y>0) ? __expf(e1-m) : 0.f;
    float p2 = (av.z>0) ? __expf(e2-m) : 0.f;
    float p3 = (av.w>0) ? __expf(e3-m) : 0.f;
    float s = wave_sum(p0+p1+p2+p3);
    float inv = 1.f/s;
    unsigned int w0 = pk16(p0*inv, p1*inv);
    unsigned int w1 = pk16(p2*inv, p3*inv);
    int off = il*512 + ((lane*8) ^ ((il&7)<<4));
    *(u32x2*)(attH + off) = (u32x2){w0,w1};
  }

  // ---- phase 2: O[i][d] = att @ h via MFMA; B staged via global_load_lds ----
  int wm = w >> 1, wn = w & 1;
  int lrow = lane & 15, kb = lane >> 4;
  int rg = lane >> 4, cc = lane & 15;
  float lf=(float)left[b], aspf=(float)asp[b], tlf=(float)tl[b];
  float rrv=lf+aspf-1.f, ctx=tlf-aspf;
  int arow = wm*16 + lrow;
  int aswz = (arow&7)<<4;

  for(int dp=0; dp<2; dp++){
    int d0 = dp*256;
    f32x4 acc[8];
    #pragma unroll
    for(int ni=0;ni<8;ni++) acc[ni] = (f32x4){0.f,0.f,0.f,0.f};
    for(int ks=0; ks<8; ks++){
      int j0 = ks*32;
      __syncthreads();   // previous tile fully consumed (also orders att writes)
      #pragma unroll
      for(int u=0;u<4;u++){
        int chunk = (u*4 + w)*64 + lane;
        int row = chunk >> 2, sl = chunk & 3;
        GLOAD16(HH + (size_t)(d0+row)*256 + j0 + sl*8, BsH + (u*4+w)*1024);
      }
      __syncthreads();   // loads landed
      int aoff = arow*512 + ((j0*2 + kb*16) ^ aswz);
      f16x8 ah = *(const f16x8*)(attH + aoff);
      #pragma unroll
      for(int ni=0; ni<8; ni++){
        f16x8 bh = *(const f16x8*)(BsH + (wn*128 + ni*16 + lrow)*64 + kb*16);
        acc[ni] = __builtin_amdgcn_mfma_f32_16x16x32_f16(ah, bh, acc[ni], 0,0,0);
      }
    }
    #pragma unroll
    for(int q=0;q<4;q++){
      int row = i0 + wm*16 + rg*4 + q;
      float fi = (float)row;
      float wgt;
      if(fi < lf)        wgt = 1.f-(lf-fi)/ctx;
      else if(fi <= rrv) wgt = 0.f;
      else if(fi < tlf)  wgt = 1.f-(fi-rrv)/ctx;
      else               wgt = 0.f;
      #pragma unroll
      for(int ni=0;ni<8;ni++){
        int col = d0 + wn*128 + ni*16 + cc;
        PA[((size_t)b*NLQ + row)*ND + col] = wgt*fmaxf(acc[ni][q], 0.f);
      }
    }
  }
}

// T[l][b*256+j] = h1[b,j,:] . v_l
__global__ __launch_bounds__(256) void k_tv(const float* __restrict__ h1,
                                            const float* __restrict__ v,
                                            float* __restrict__ T){
  int row  = blockIdx.x*4 + (threadIdx.x>>6);
  int lane = threadIdx.x & 63;
  const float4* hr = (const float4*)(h1 + (size_t)row*ND);
  float4 h0 = hr[lane], h1v = hr[lane+64];
  float s0,s1,s2,s3,s4;
  #define DOTV(SL, L) { \
    const float4* vr = (const float4*)(v + (L)*ND); \
    float4 v0 = vr[lane], v1 = vr[lane+64]; \
    float dd = h0.x*v0.x+h0.y*v0.y+h0.z*v0.z+h0.w*v0.w \
             + h1v.x*v1.x+h1v.y*v1.y+h1v.z*v1.z+h1v.w*v1.w; \
    SL = wave_sum(dd); }
  DOTV(s0,0) DOTV(s1,1) DOTV(s2,2) DOTV(s3,3) DOTV(s4,4)
  #undef DOTV
  if(lane==0){
    T[0*32768 + row]=s0; T[1*32768 + row]=s1; T[2*32768 + row]=s2;
    T[3*32768 + row]=s3; T[4*32768 + row]=s4;
  }
}

__global__ __launch_bounds__(256) void k_rows(const float* __restrict__ h1,
                                              const int* __restrict__ left, const int* __restrict__ asp,
                                              float* __restrict__ R){
  int b = blockIdx.x;
  int nk = asp[b], l0 = left[b];
  const float4* src = (const float4*)(h1 + (size_t)b*NLQ*ND);
  float4* dst = (float4*)(R + (size_t)b*8*ND);
  #pragma unroll
  for(int u=0; u<4; u++){
    int f4 = threadIdx.x + u*256;
    int k = f4 >> 7, c = f4 & 127;
    float4 val = (k<nk) ? src[(size_t)(l0+k)*128 + c] : (float4){0.f,0.f,0.f,0.f};
    dst[f4] = val;
  }
}

// one block per (layer, batch): 5 aspect-row atts + y = att @ h1.
// bid = l*128 + b  ->  all 5 layer-blocks of batch b on same XCD (128 % 8 == 0).
__global__ __launch_bounds__(256) void k_att5(const float* __restrict__ h1,
    const float* __restrict__ Hasp, const float* __restrict__ T,
    const int* __restrict__ adj, const float* __restrict__ scal,
    const int* __restrict__ left, const int* __restrict__ asp,
    float* __restrict__ y){
  __shared__ float att[5][260];
  int b  = blockIdx.x & 127;
  int l  = blockIdx.x >> 7;
  int tid = threadIdx.x, lane = tid&63, w = tid>>6;
  int nk = asp[b], l0 = left[b];
  float S0 = scal[2*(l+1)], S1 = scal[2*(l+1)+1];

  for(int k = w; k < 5; k += 4){
    if(k < nk){
      const float2* hrow = (const float2*)(Hasp + (size_t)l*MN + (size_t)(b*8+k)*ND);
      const int* arow = adj + ((size_t)b*NLQ + (l0+k))*NLQ;
      const float* Tl = T + l*32768 + b*256;
      float e[4]; int av[4];
      float m = -3.0e38f;
      #pragma unroll
      for(int q=0;q<4;q++){
        int j = lane + 64*q;
        float2 hp = hrow[j];
        av[q] = arow[j];
        e[q] = fmaxf(S0*hp.x + S1*hp.y + Tl[j], 0.f);
        if(av[q] > 0) m = fmaxf(m, e[q]);
      }
      m = wave_max(m);
      float pp[4]; float s = 0.f;
      #pragma unroll
      for(int q=0;q<4;q++){
        pp[q] = (av[q] > 0) ? __expf(e[q]-m) : 0.f;
        s += pp[q];
      }
      s = wave_sum(s);
      float inv = 1.f/s;
      #pragma unroll
      for(int q=0;q<4;q++) att[k][lane+64*q] = pp[q]*inv;
    } else {
      #pragma unroll
      for(int q=0;q<4;q++) att[k][lane+64*q] = 0.f;
    }
  }
  __syncthreads();

  int d = tid;
  const float* hb = h1 + (size_t)b*NLQ*ND;
  float ax[5] = {0,0,0,0,0}, ay[5] = {0,0,0,0,0};
  for(int jj=0; jj<NLQ; jj++){
    float hx = hb[(size_t)jj*ND + d];
    float hy = hb[(size_t)jj*ND + 256 + d];
    #pragma unroll
    for(int k=0;k<5;k++){
      float a = att[k][jj];
      ax[k] += a*hx;
      ay[k] += a*hy;
    }
  }
  float* yb = y + (size_t)l*MN + (size_t)b*8*ND;
  #pragma unroll
  for(int k=0;k<5;k++){
    yb[(size_t)k*ND + d]       = ax[k];
    yb[(size_t)k*ND + 256 + d] = ay[k];
  }
  #pragma unroll
  for(int u=0;u<6;u++) yb[5*ND + u*256 + tid] = 0.f;
}

__global__ __launch_bounds__(256) void k_g(const float* __restrict__ hp,
    const int* __restrict__ asp, float* __restrict__ g){
  int b = blockIdx.x, d = threadIdx.x;
  int nk = asp[b];
  float gx=0.f, gy=0.f;
  for(int l=0;l<5;l++){
    for(int k=0;k<nk;k++){
      const float* r = hp + (size_t)l*MN + (size_t)(b*8+k)*ND;
      gx += fmaxf(r[d], 0.f);
      gy += fmaxf(r[d+256], 0.f);
    }
  }
  g[b*ND + d]       = 0.2f*gx;
  g[b*ND + 256 + d] = 0.2f*gy;
}

__global__ __launch_bounds__(256) void k_dot(const float* __restrict__ x,
    const float* __restrict__ g, float* __restrict__ s){
  int row  = blockIdx.x*4 + (threadIdx.x>>6);
  int b    = row >> 8;
  int lane = threadIdx.x & 63;
  const float4* xr = (const float4*)(x + (size_t)row*ND);
  const float4* gr = (const float4*)(g + (size_t)b*ND);
  float4 x0=xr[lane], x1=xr[lane+64], g0=gr[lane], g1=gr[lane+64];
  float d = x0.x*g0.x + x0.y*g0.y + x0.z*g0.z + x0.w*g0.w
          + x1.x*g1.x + x1.y*g1.y + x1.z*g1.z + x1.w*g1.w;
  d = wave_sum(d);
  if(lane==0) s[row] = d;
}

__global__ __launch_bounds__(256) void k_out(const float* __restrict__ x,
    const float* __restrict__ s, float* __restrict__ out){
  int b  = blockIdx.x >> 2;
  int ch = blockIdx.x & 3;
  int tid = threadIdx.x, lane = tid&63, w = tid>>6;
  __shared__ float red[4];
  __shared__ float alpha[NLQ];
  __shared__ float part[128];
  float sv = s[b*NLQ + tid];
  float m = wave_max(sv);
  if(lane==0) red[w] = m;
  __syncthreads();
  m = fmaxf(fmaxf(red[0],red[1]), fmaxf(red[2],red[3]));
  float p = __expf(sv - m);
  float su = wave_sum(p);
  __syncthreads();
  if(lane==0) red[w] = su;
  __syncthreads();
  su = red[0]+red[1]+red[2]+red[3];
  alpha[tid] = p/su;
  __syncthreads();
  int d = ch*128 + (tid & 127);
  int half = tid >> 7;
  const float* xb = x + (size_t)b*NLQ*ND;
  float acc = 0.f;
  for(int mm = half*128; mm < half*128 + 128; mm++)
    acc += alpha[mm] * xb[(size_t)mm*ND + d];
  if(half) part[tid & 127] = acc;
  __syncthreads();
  if(!half) out[(size_t)b*ND + d] = acc + part[tid & 127];
}

extern "C" void kernel_launch(void* const* d_in, const int* in_sizes, int n_in,
                              void* d_out, int out_size, void* d_ws, size_t ws_size,
                              hipStream_t stream){
  const float* x    = (const float*)d_in[0];
  const float* Wst  = (const float*)d_in[1];
  const float* ast  = (const float*)d_in[2];
  const int*   adj  = (const int*)d_in[3];
  const int*   left = (const int*)d_in[4];
  const int*   asp  = (const int*)d_in[5];
  const int*   tl   = (const int*)d_in[6];
  float* out = (float*)d_out;
  float* ws  = (float*)d_ws;

  const size_t SZ = (size_t)NB*NLQ*ND;
  float* bufA = ws;                     // P (fp16, packed per tile) -> h1 (block-local overwrite)
  float* bufB = ws + SZ;                // fp16 hT plane; later Hasp/ybuf/hp/R/Wt15
  float* ws2  = ws + 2*SZ;
  float* tpart= ws2;                    // 4*32768
  float* T    = tpart + 4*32768;        // 163840
  float* g    = T + 163840;             // 65536
  float* scal = g + 65536;              // 16
  float* v    = scal + 16;              // 2560
  float* sbuf = v + 2560;               // 32768
  ushort_t* w0th = (ushort_t*)(sbuf + 32768);  // DD ushorts (layer-0 Wt fp16) in proven 1MB slot

  ushort_t* hTH = (ushort_t*)bufB;             // NB*HTB fp16

  float* Hasp = bufB;                   // reuse after k_attn0
  float* ybuf = Hasp + (size_t)5*MN;
  float* hp   = ybuf + (size_t)5*MN;
  float* R    = hp   + (size_t)5*MN;    // MN floats
  ushort_t* wt15h = (ushort_t*)(R + MN);       // 5*DD ushorts

  k_scal<<<NLAYERS, 256, 0, stream>>>(ast, scal);
  k_wa2<<<5*128, 256, 0, stream>>>(Wst, ast, v);
  k_wcvt<<<64, 256, 0, stream>>>(Wst, w0th);

  // layer 0: posw fused in A-stage; emits fp16 plane + fp16 pair-scores P + t-partials
  k_gemm_t<<<(NB*NLQ/128)*(ND/128), 256, 0, stream>>>(x, w0th,
      (unsigned int*)hTH, (ushort_t*)bufA, tpart, ast + ND, scal, left, asp, tl);
  k_attn0<<<NB*8, 256, 0, stream>>>(hTH, adj, tpart, left, asp, tl, bufA);

  // layers 1..5 on aspect rows only
  k_wcvt<<<5*64, 256, 0, stream>>>(Wst + DD, wt15h);
  k_tv<<<NB*NLQ/4, 256, 0, stream>>>(bufA, v, T);
  k_rows<<<NB, 256, 0, stream>>>(bufA, left, asp, R);
  k_gemm_b<<<5*32, 256, 0, stream>>>(R, 0L, wt15h, Hasp);
  k_att5<<<5*NB, 256, 0, stream>>>(bufA, Hasp, T, adj, scal, left, asp, ybuf);
  k_gemm_b<<<5*32, 256, 0, stream>>>(ybuf, (long)MN, wt15h, hp);
  k_g<<<NB, 256, 0, stream>>>(hp, asp, g);

  // final attention over original x
  k_dot<<<NB*NLQ/4, 256, 0, stream>>>(x, g, sbuf);
  k_out<<<NB*4, 256, 0, stream>>>(x, sbuf, out);
}

// Round 14
// 214.053 us; speedup vs baseline: 1.5385x; 1.0062x over previous
//
#include <hip/hip_runtime.h>

#define NB 128
#define NLQ 256   // sequence length L
#define ND 512    // feature dim D
#define NLAYERS 6
#define DD (ND*ND)
#define MN (1024*ND)
#define HTB 131072   // fp16 elems per batch in hT plane: 512*256

typedef _Float16 f16x8 __attribute__((ext_vector_type(8)));
typedef __fp16 fp16x2 __attribute__((ext_vector_type(2)));
typedef _Float16 f16x4v __attribute__((ext_vector_type(4)));
typedef float f32x4 __attribute__((ext_vector_type(4)));
typedef unsigned int u32x2 __attribute__((ext_vector_type(2)));
typedef unsigned int u32x4 __attribute__((ext_vector_type(4)));
typedef unsigned short ushort_t;

#define GLOAD16(gp, lp) __builtin_amdgcn_global_load_lds( \
    (const __attribute__((address_space(1))) void*)(gp), \
    (__attribute__((address_space(3))) void*)(lp), 16, 0, 0)

__device__ __forceinline__ float wave_max(float v){
  #pragma unroll
  for(int off=32; off; off>>=1) v = fmaxf(v, __shfl_xor(v, off));
  return v;
}
__device__ __forceinline__ float wave_sum(float v){
  #pragma unroll
  for(int off=32; off; off>>=1) v += __shfl_xor(v, off);
  return v;
}
// pack two fp32 into one dword of fp16 (v_cvt_pkrtz_f16_f32, single instr)
__device__ __forceinline__ unsigned int pk16(float a, float b){
  fp16x2 h = __builtin_amdgcn_cvt_pkrtz(a, b);
  return __builtin_bit_cast(unsigned int, h);
}

__global__ __launch_bounds__(256) void k_scal(const float* __restrict__ a_stack,
                                              float* __restrict__ scal){
  int layer = blockIdx.x;
  const float* a = a_stack + (size_t)layer*2*ND;
  int t = threadIdx.x;
  float v0 = a[t];
  float v1 = a[256 + t];
  v0 = wave_sum(v0); v1 = wave_sum(v1);
  __shared__ float s0[4], s1[4];
  int wave = t>>6, lane = t&63;
  if(lane==0){ s0[wave]=v0; s1[wave]=v1; }
  __syncthreads();
  if(t==0){
    scal[layer*2+0] = s0[0]+s0[1]+s0[2]+s0[3];
    scal[layer*2+1] = s1[0]+s1[1]+s1[2]+s1[3];
  }
}

// v_l[i] = dot(W_{l+1}[i,:], a2_{l+1})
__global__ __launch_bounds__(256) void k_wa2(const float* __restrict__ Wst,
                                             const float* __restrict__ ast,
                                             float* __restrict__ v){
  int l  = blockIdx.x >> 7;
  int rg = blockIdx.x & 127;
  int i  = rg*4 + (threadIdx.x>>6);
  int lane = threadIdx.x & 63;
  const float4* wr = (const float4*)(Wst + (size_t)(l+1)*DD + (size_t)i*ND);
  const float4* ar = (const float4*)(ast + (size_t)(l+1)*2*ND + ND);
  float4 w0=wr[lane], w1=wr[lane+64], a0=ar[lane], a1=ar[lane+64];
  float d = w0.x*a0.x + w0.y*a0.y + w0.z*a0.z + w0.w*a0.w
          + w1.x*a1.x + w1.y*a1.y + w1.z*a1.z + w1.w*a1.w;
  d = wave_sum(d);
  if(lane==0) v[l*ND + i] = d;
}

// transpose + convert W layers to single fp16 plane Wt[n][k]. One 64x64 tile per block.
__global__ __launch_bounds__(256) void k_wcvt(const float* __restrict__ Wsrc,
                                              ushort_t* __restrict__ Ho){
  __shared__ float CT[64][65];
  int bid = blockIdx.x;
  int l  = bid >> 6;
  int kt = (bid >> 3) & 7, nt = bid & 7;
  const float* Wl = Wsrc + (size_t)l*DD;
  int t = threadIdx.x;
  int r = t >> 2, c4 = (t&3)*16;
  #pragma unroll
  for(int u=0;u<4;u++){
    float4 vv = *(const float4*)(Wl + (size_t)(kt*64+r)*ND + nt*64 + c4 + u*4);
    CT[r][c4+u*4+0]=vv.x; CT[r][c4+u*4+1]=vv.y;
    CT[r][c4+u*4+2]=vv.z; CT[r][c4+u*4+3]=vv.w;
  }
  __syncthreads();
  int n = t >> 2, kc = t & 3;
  unsigned int o[8];
  #pragma unroll
  for(int j=0;j<8;j++)
    o[j] = pk16(CT[kc*16 + 2*j][n], CT[kc*16 + 2*j + 1][n]);
  ushort_t* dh = Ho + (size_t)l*DD + (size_t)(nt*64+n)*ND + kt*64 + kc*16;
  *(u32x4*)(dh)     = (u32x4){o[0],o[1],o[2],o[3]};
  *(u32x4*)(dh + 8) = (u32x4){o[4],o[5],o[6],o[7]};
}

// ---- fp16 MFMA GEMM tile, BK=64: C[128x128] = A[128x512]@W[512x128] ----
// W pre-converted/transposed as fp16 plane Wt[n][k]. A fp32, converted in staging.
// MODE=0: C row-major [M][512].
// MODE=1: posw fused into A-stage; outputs transposed fp16 plane hP[b][d][i],
//         Pscore fp16 (packed per tile), t-partials tp4.
#define ROWB2 144   // 64 fp16 = 128B data + 16B pad
template<int MODE>
__device__ __forceinline__ void gemm_tile(const float* __restrict__ A,
                                          const ushort_t* __restrict__ Wth,
                                          float* __restrict__ C,
                                          unsigned int* __restrict__ hP,
                                          ushort_t* __restrict__ Pbuf,
                                          float* __restrict__ tp4,
                                          const float* __restrict__ a2,
                                          const float* __restrict__ scal,
                                          const int* __restrict__ left,
                                          const int* __restrict__ asp,
                                          const int* __restrict__ tl,
                                          int mtile, int ntile, unsigned char* lds){
  unsigned char* Ah = lds;                  // 128*144
  unsigned char* Bh = lds + 128*ROWB2;      // 128*144

  int t = threadIdx.x;
  int m0 = mtile*128, n0 = ntile*128;
  int lane = t & 63, wid = t >> 6;
  int wr = wid >> 1, wc = wid & 1;
  int lrow = lane & 15, kb = lane >> 4;

  f32x4 acc[4][4];
  #pragma unroll
  for(int mi=0;mi<4;mi++)
    #pragma unroll
    for(int ni=0;ni<4;ni++)
      acc[mi][ni] = (f32x4){0.f,0.f,0.f,0.f};

  int a_row = t >> 4;       // 0..15 (+p*16, 8 p's)
  int a_sl  = t & 15;       // float4 slot within 64-k row
  int w_n   = t >> 1;       // 0..127
  int w_sl  = t & 1;        // half of the 8 16B-slots

  float wgt_[8] = {1.f,1.f,1.f,1.f,1.f,1.f,1.f,1.f};
  if(MODE == 1){
    int b = mtile >> 1;
    float lf=(float)left[b], aspf=(float)asp[b], tlf=(float)tl[b];
    float rr=lf+aspf-1.f, ctx=tlf-aspf;
    #pragma unroll
    for(int p=0;p<8;p++){
      float jf = (float)((mtile&1)*128 + a_row + p*16);
      float w;
      if(jf < lf)       w = 1.f-(lf-jf)/ctx;
      else if(jf <= rr) w = 0.f;
      else if(jf < tlf) w = 1.f-(jf-rr)/ctx;
      else              w = 0.f;
      wgt_[p] = w;
    }
  }

  float4 pa[8];
  u32x4 pwh[4];

  #pragma unroll
  for(int p=0;p<8;p++)
    pa[p] = *(const float4*)(A + (size_t)(m0 + a_row + p*16)*ND + a_sl*4);
  #pragma unroll
  for(int i=0;i<4;i++)
    pwh[i] = *(const u32x4*)(Wth + (size_t)(n0 + w_n)*ND + (w_sl*4+i)*8);

  for(int k0=0; k0<ND; k0+=64){
    #pragma unroll
    for(int p=0;p<8;p++){
      unsigned int c0 = pk16(pa[p].x*wgt_[p], pa[p].y*wgt_[p]);
      unsigned int c1 = pk16(pa[p].z*wgt_[p], pa[p].w*wgt_[p]);
      *(u32x2*)(Ah + (a_row + p*16)*ROWB2 + a_sl*8) = (u32x2){c0, c1};
    }
    #pragma unroll
    for(int i=0;i<4;i++)
      *(u32x4*)(Bh + w_n*ROWB2 + (w_sl*4+i)*16) = pwh[i];
    __syncthreads();

    if(k0 + 64 < ND){
      int kn = k0 + 64;
      #pragma unroll
      for(int p=0;p<8;p++)
        pa[p] = *(const float4*)(A + (size_t)(m0 + a_row + p*16)*ND + kn + a_sl*4);
      #pragma unroll
      for(int i=0;i<4;i++)
        pwh[i] = *(const u32x4*)(Wth + (size_t)(n0 + w_n)*ND + kn + (w_sl*4+i)*8);
    }

    #pragma unroll
    for(int ks=0; ks<2; ks++){
      f16x8 ah[4], bh[4];
      #pragma unroll
      for(int mi=0;mi<4;mi++)
        ah[mi] = *(const f16x8*)(Ah + (wr*64 + mi*16 + lrow)*ROWB2 + ks*64 + kb*16);
      #pragma unroll
      for(int ni=0;ni<4;ni++)
        bh[ni] = *(const f16x8*)(Bh + (wc*64 + ni*16 + lrow)*ROWB2 + ks*64 + kb*16);
      #pragma unroll
      for(int mi=0;mi<4;mi++)
        #pragma unroll
        for(int ni=0;ni<4;ni++)
          acc[mi][ni] = __builtin_amdgcn_mfma_f32_16x16x32_f16(ah[mi], bh[ni], acc[mi][ni], 0,0,0);
    }
    __syncthreads();
  }

  int rg = lane >> 4;
  int cc = lane & 15;
  if(MODE == 0){
    #pragma unroll
    for(int mi=0;mi<4;mi++)
      #pragma unroll
      for(int ni=0;ni<4;ni++){
        int col = n0 + wc*64 + ni*16 + cc;
        #pragma unroll
        for(int q=0;q<4;q++){
          int row = m0 + wr*64 + mi*16 + rg*4 + q;
          C[(size_t)row*ND + col] = acc[mi][ni][q];
        }
      }
  } else {
    float S0 = scal[0], S1 = scal[1];
    float* CT = (float*)lds;   // 64*130 floats = 33280 B (fits in 36864 staging LDS)
    int b = m0 >> 8;
    int ibase = m0 & 255;
    int tr   = t >> 1;
    int tch  = t & 1;
    float tpsum = 0.f;
    #pragma unroll
    for(int p=0;p<2;p++){
      if(wc == p){
        #pragma unroll
        for(int mi=0;mi<4;mi++)
          #pragma unroll
          for(int ni=0;ni<4;ni++)
            #pragma unroll
            for(int q=0;q<4;q++)
              CT[(ni*16+cc)*130 + wr*64 + mi*16 + rg*4 + q] = acc[mi][ni][q];
      }
      __syncthreads();
      // transposed fp16 plane [b][d][i]
      int lcol = t >> 6;
      int lrow2 = (t & 63)*2;
      #pragma unroll
      for(int u=0;u<16;u++){
        int c = lcol + u*4;
        float2 v2 = *(float2*)&CT[c*130 + lrow2];
        size_t uidx = ((size_t)b*HTB + (size_t)(n0 + p*64 + c)*256 + ibase + lrow2) >> 1;
        hP[uidx] = pk16(v2.x, v2.y);
      }
      // Pscore: pair-reduced scores, fp16, packed into the (b,itile) h1 region
      {
        int cpr = t & 31;
        int rq  = t >> 5;
        #pragma unroll
        for(int rr2=0; rr2<16; rr2++){
          int row = rq*16 + rr2;
          float pval = S0*CT[(2*cpr)*130 + row] + S1*CT[(2*cpr+1)*130 + row];
          int ig = ibase + row;
          _Float16 ph = (_Float16)pval;
          size_t addr = (size_t)b*262144 + (size_t)(ig>>5)*32768
                      + (size_t)(ig&31)*256 + (n0>>1) + p*32 + cpr;
          Pbuf[addr] = __builtin_bit_cast(unsigned short, ph);
        }
      }
      // t-partial over this 64-d slab
      #pragma unroll 8
      for(int cc2=0; cc2<32; cc2++){
        int c = tch*32 + cc2;
        tpsum = fmaf(CT[c*130 + tr], a2[n0 + p*64 + c], tpsum);
      }
      __syncthreads();
    }
    tpsum += __shfl_xor(tpsum, 1);
    if(tch == 0) tp4[(n0>>7)*32768 + m0 + tr] = tpsum;
  }
}

__global__ __launch_bounds__(256) void k_gemm_t(const float* __restrict__ A,
                                                const ushort_t* __restrict__ Wth,
                                                unsigned int* __restrict__ hP,
                                                ushort_t* __restrict__ Pbuf,
                                                float* __restrict__ tp4,
                                                const float* __restrict__ a2,
                                                const float* __restrict__ scal,
                                                const int* __restrict__ left,
                                                const int* __restrict__ asp,
                                                const int* __restrict__ tl){
  __shared__ unsigned char lds[2*128*ROWB2];   // 36864 B
  // XCD swizzle: 4 n-tiles of each m-tile within 32 consecutive bids, all same (bid mod 8)
  int bid = blockIdx.x;
  int ntile = (bid >> 3) & 3;
  int mtile = (bid & 7) | ((bid >> 5) << 3);
  gemm_tile<1>(A, Wth, nullptr, hP, Pbuf, tp4, a2, scal, left, asp, tl,
               mtile, ntile, lds);
}

__global__ __launch_bounds__(256) void k_gemm_b(const float* __restrict__ Abase, long aStride,
                                                const ushort_t* __restrict__ Wth,
                                                float* __restrict__ Cbase){
  __shared__ unsigned char lds[2*128*ROWB2];
  int l  = blockIdx.x >> 5;
  int tb = blockIdx.x & 31;
  gemm_tile<0>(Abase + (size_t)l*aStride, Wth + (size_t)l*DD,
               Cbase + (size_t)l*MN, nullptr, nullptr, nullptr,
               nullptr, nullptr, nullptr, nullptr, nullptr, tb>>2, tb&3, lds);
}

// layer-0 attention: coalesced fp16-P softmax (lanes=j, adj direct int4)
// + MFMA aggregation (att fp16, h plane fp16, 1 MFMA/frag) with global_load_lds B staging.
__global__ __launch_bounds__(256) void k_attn0(
    const ushort_t* __restrict__ hTH,
    const int* __restrict__ adj,
    const float* __restrict__ tpart,
    const int* __restrict__ left, const int* __restrict__ asp, const int* __restrict__ tl,
    float* __restrict__ PA){
  __shared__ unsigned char attH[32*512];   // fp16 att [32 i][256 j], XOR-swizzled
  __shared__ unsigned char BsH[16384];     // staged fp16 plane [256 d][32 j] linear 64B rows

  int bid = blockIdx.x;
  int b  = bid & 127;      // 8 blocks of batch b land on same XCD
  int ic = bid >> 7;
  int i0 = ic*32;
  int tid = threadIdx.x;
  int lane = tid & 63, w = tid >> 6;
  const ushort_t* HH = hTH + (size_t)b*HTB;
  const ushort_t* Pt = (const ushort_t*)PA + (size_t)b*262144 + (size_t)ic*32768;

  // ---- phase 1: softmax, lanes = j (4 j's per lane) ----
  float t0v=0.f, t1v=0.f, t2v=0.f, t3v=0.f;
  #pragma unroll
  for(int nt=0; nt<4; nt++){
    float4 tv = ((const float4*)(tpart + nt*32768 + b*256))[lane];
    t0v += tv.x; t1v += tv.y; t2v += tv.z; t3v += tv.w;
  }

  for(int rr=0; rr<8; rr++){
    int il = w*8 + rr;         // 0..31
    int i  = i0 + il;
    f16x4v pv = *(const f16x4v*)(Pt + il*256 + lane*4);
    int4 av = ((const int4*)(adj + ((size_t)b*NLQ + i)*NLQ))[lane];
    float e0 = fmaxf((float)pv[0] + t0v, 0.f);
    float e1 = fmaxf((float)pv[1] + t1v, 0.f);
    float e2 = fmaxf((float)pv[2] + t2v, 0.f);
    float e3 = fmaxf((float)pv[3] + t3v, 0.f);
    float m = -3.0e38f;
    if(av.x>0) m = e0;
    if(av.y>0) m = fmaxf(m, e1);
    if(av.z>0) m = fmaxf(m, e2);
    if(av.w>0) m = fmaxf(m, e3);
    m = wave_max(m);
    float p0 = (av.x>0) ? __expf(e0-m) : 0.f;
    float p1 = (av.y>0) ? __expf(e1-m) : 0.f;
    float p2 = (av.z>0) ? __expf(e2-m) : 0.f;
    float p3 = (av.w>0) ? __expf(e3-m) : 0.f;
    float s = wave_sum(p0+p1+p2+p3);
    float inv = 1.f/s;
    unsigned int w0 = pk16(p0*inv, p1*inv);
    unsigned int w1 = pk16(p2*inv, p3*inv);
    int off = il*512 + ((lane*8) ^ ((il&7)<<4));
    *(u32x2*)(attH + off) = (u32x2){w0,w1};
  }

  // ---- phase 2: O[i][d] = att @ h via MFMA; B staged via global_load_lds ----
  int wm = w >> 1, wn = w & 1;
  int lrow = lane & 15, kb = lane >> 4;
  int rg = lane >> 4, cc = lane & 15;
  float lf=(float)left[b], aspf=(float)asp[b], tlf=(float)tl[b];
  float rrv=lf+aspf-1.f, ctx=tlf-aspf;
  int arow = wm*16 + lrow;
  int aswz = (arow&7)<<4;

  for(int dp=0; dp<2; dp++){
    int d0 = dp*256;
    f32x4 acc[8];
    #pragma unroll
    for(int ni=0;ni<8;ni++) acc[ni] = (f32x4){0.f,0.f,0.f,0.f};
    for(int ks=0; ks<8; ks++){
      int j0 = ks*32;
      __syncthreads();   // previous tile fully consumed (also orders att writes)
      #pragma unroll
      for(int u=0;u<4;u++){
        int chunk = (u*4 + w)*64 + lane;
        int row = chunk >> 2, sl = chunk & 3;
        GLOAD16(HH + (size_t)(d0+row)*256 + j0 + sl*8, BsH + (u*4+w)*1024);
      }
      __syncthreads();   // loads landed
      int aoff = arow*512 + ((j0*2 + kb*16) ^ aswz);
      f16x8 ah = *(const f16x8*)(attH + aoff);
      #pragma unroll
      for(int ni=0; ni<8; ni++){
        f16x8 bh = *(const f16x8*)(BsH + (wn*128 + ni*16 + lrow)*64 + kb*16);
        acc[ni] = __builtin_amdgcn_mfma_f32_16x16x32_f16(ah, bh, acc[ni], 0,0,0);
      }
    }
    #pragma unroll
    for(int q=0;q<4;q++){
      int row = i0 + wm*16 + rg*4 + q;
      float fi = (float)row;
      float wgt;
      if(fi < lf)        wgt = 1.f-(lf-fi)/ctx;
      else if(fi <= rrv) wgt = 0.f;
      else if(fi < tlf)  wgt = 1.f-(fi-rrv)/ctx;
      else               wgt = 0.f;
      #pragma unroll
      for(int ni=0;ni<8;ni++){
        int col = d0 + wn*128 + ni*16 + cc;
        PA[((size_t)b*NLQ + row)*ND + col] = wgt*fmaxf(acc[ni][q], 0.f);
      }
    }
  }
}

// T[l][b*256+j] = h1[b,j,:] . v_l
__global__ __launch_bounds__(256) void k_tv(const float* __restrict__ h1,
                                            const float* __restrict__ v,
                                            float* __restrict__ T){
  int row  = blockIdx.x*4 + (threadIdx.x>>6);
  int lane = threadIdx.x & 63;
  const float4* hr = (const float4*)(h1 + (size_t)row*ND);
  float4 h0 = hr[lane], h1v = hr[lane+64];
  float s0,s1,s2,s3,s4;
  #define DOTV(SL, L) { \
    const float4* vr = (const float4*)(v + (L)*ND); \
    float4 v0 = vr[lane], v1 = vr[lane+64]; \
    float dd = h0.x*v0.x+h0.y*v0.y+h0.z*v0.z+h0.w*v0.w \
             + h1v.x*v1.x+h1v.y*v1.y+h1v.z*v1.z+h1v.w*v1.w; \
    SL = wave_sum(dd); }
  DOTV(s0,0) DOTV(s1,1) DOTV(s2,2) DOTV(s3,3) DOTV(s4,4)
  #undef DOTV
  if(lane==0){
    T[0*32768 + row]=s0; T[1*32768 + row]=s1; T[2*32768 + row]=s2;
    T[3*32768 + row]=s3; T[4*32768 + row]=s4;
  }
}

__global__ __launch_bounds__(256) void k_rows(const float* __restrict__ h1,
                                              const int* __restrict__ left, const int* __restrict__ asp,
                                              float* __restrict__ R){
  int b = blockIdx.x;
  int nk = asp[b], l0 = left[b];
  const float4* src = (const float4*)(h1 + (size_t)b*NLQ*ND);
  float4* dst = (float4*)(R + (size_t)b*8*ND);
  #pragma unroll
  for(int u=0; u<4; u++){
    int f4 = threadIdx.x + u*256;
    int k = f4 >> 7, c = f4 & 127;
    float4 val = (k<nk) ? src[(size_t)(l0+k)*128 + c] : (float4){0.f,0.f,0.f,0.f};
    dst[f4] = val;
  }
}

// one block per (layer, batch): 5 aspect-row atts + y = att @ h1.
// bid = l*128 + b  ->  all 5 layer-blocks of batch b on same XCD (128 % 8 == 0).
__global__ __launch_bounds__(256) void k_att5(const float* __restrict__ h1,
    const float* __restrict__ Hasp, const float* __restrict__ T,
    const int* __restrict__ adj, const float* __restrict__ scal,
    const int* __restrict__ left, const int* __restrict__ asp,
    float* __restrict__ y){
  __shared__ float att[5][260];
  int b  = blockIdx.x & 127;
  int l  = blockIdx.x >> 7;
  int tid = threadIdx.x, lane = tid&63, w = tid>>6;
  int nk = asp[b], l0 = left[b];
  float S0 = scal[2*(l+1)], S1 = scal[2*(l+1)+1];

  for(int k = w; k < 5; k += 4){
    if(k < nk){
      const float2* hrow = (const float2*)(Hasp + (size_t)l*MN + (size_t)(b*8+k)*ND);
      const int* arow = adj + ((size_t)b*NLQ + (l0+k))*NLQ;
      const float* Tl = T + l*32768 + b*256;
      float e[4]; int av[4];
      float m = -3.0e38f;
      #pragma unroll
      for(int q=0;q<4;q++){
        int j = lane + 64*q;
        float2 hp = hrow[j];
        av[q] = arow[j];
        e[q] = fmaxf(S0*hp.x + S1*hp.y + Tl[j], 0.f);
        if(av[q] > 0) m = fmaxf(m, e[q]);
      }
      m = wave_max(m);
      float pp[4]; float s = 0.f;
      #pragma unroll
      for(int q=0;q<4;q++){
        pp[q] = (av[q] > 0) ? __expf(e[q]-m) : 0.f;
        s += pp[q];
      }
      s = wave_sum(s);
      float inv = 1.f/s;
      #pragma unroll
      for(int q=0;q<4;q++) att[k][lane+64*q] = pp[q]*inv;
    } else {
      #pragma unroll
      for(int q=0;q<4;q++) att[k][lane+64*q] = 0.f;
    }
  }
  __syncthreads();

  int d = tid;
  const float* hb = h1 + (size_t)b*NLQ*ND;
  float ax[5] = {0,0,0,0,0}, ay[5] = {0,0,0,0,0};
  for(int jj=0; jj<NLQ; jj++){
    float hx = hb[(size_t)jj*ND + d];
    float hy = hb[(size_t)jj*ND + 256 + d];
    #pragma unroll
    for(int k=0;k<5;k++){
      float a = att[k][jj];
      ax[k] += a*hx;
      ay[k] += a*hy;
    }
  }
  float* yb = y + (size_t)l*MN + (size_t)b*8*ND;
  #pragma unroll
  for(int k=0;k<5;k++){
    yb[(size_t)k*ND + d]       = ax[k];
    yb[(size_t)k*ND + 256 + d] = ay[k];
  }
  #pragma unroll
  for(int u=0;u<6;u++) yb[5*ND + u*256 + tid] = 0.f;
}

__global__ __launch_bounds__(256) void k_g(const float* __restrict__ hp,
    const int* __restrict__ asp, float* __restrict__ g){
  int b = blockIdx.x, d = threadIdx.x;
  int nk = asp[b];
  float gx=0.f, gy=0.f;
  for(int l=0;l<5;l++){
    for(int k=0;k<nk;k++){
      const float* r = hp + (size_t)l*MN + (size_t)(b*8+k)*ND;
      gx += fmaxf(r[d], 0.f);
      gy += fmaxf(r[d+256], 0.f);
    }
  }
  g[b*ND + d]       = 0.2f*gx;
  g[b*ND + 256 + d] = 0.2f*gy;
}

__global__ __launch_bounds__(256) void k_dot(const float* __restrict__ x,
    const float* __restrict__ g, float* __restrict__ s){
  int row  = blockIdx.x*4 + (threadIdx.x>>6);
  int b    = row >> 8;
  int lane = threadIdx.x & 63;
  const float4* xr = (const float4*)(x + (size_t)row*ND);
  const float4* gr = (const float4*)(g + (size_t)b*ND);
  float4 x0=xr[lane], x1=xr[lane+64], g0=gr[lane], g1=gr[lane+64];
  float d = x0.x*g0.x + x0.y*g0.y + x0.z*g0.z + x0.w*g0.w
          + x1.x*g1.x + x1.y*g1.y + x1.z*g1.z + x1.w*g1.w;
  d = wave_sum(d);
  if(lane==0) s[row] = d;
}

__global__ __launch_bounds__(256) void k_out(const float* __restrict__ x,
    const float* __restrict__ s, float* __restrict__ out){
  int b  = blockIdx.x >> 2;
  int ch = blockIdx.x & 3;
  int tid = threadIdx.x, lane = tid&63, w = tid>>6;
  __shared__ float red[4];
  __shared__ float alpha[NLQ];
  __shared__ float part[128];
  float sv = s[b*NLQ + tid];
  float m = wave_max(sv);
  if(lane==0) red[w] = m;
  __syncthreads();
  m = fmaxf(fmaxf(red[0],red[1]), fmaxf(red[2],red[3]));
  float p = __expf(sv - m);
  float su = wave_sum(p);
  __syncthreads();
  if(lane==0) red[w] = su;
  __syncthreads();
  su = red[0]+red[1]+red[2]+red[3];
  alpha[tid] = p/su;
  __syncthreads();
  int d = ch*128 + (tid & 127);
  int half = tid >> 7;
  const float* xb = x + (size_t)b*NLQ*ND;
  float acc = 0.f;
  for(int mm = half*128; mm < half*128 + 128; mm++)
    acc += alpha[mm] * xb[(size_t)mm*ND + d];
  if(half) part[tid & 127] = acc;
  __syncthreads();
  if(!half) out[(size_t)b*ND + d] = acc + part[tid & 127];
}

extern "C" void kernel_launch(void* const* d_in, const int* in_sizes, int n_in,
                              void* d_out, int out_size, void* d_ws, size_t ws_size,
                              hipStream_t stream){
  const float* x    = (const float*)d_in[0];
  const float* Wst  = (const float*)d_in[1];
  const float* ast  = (const float*)d_in[2];
  const int*   adj  = (const int*)d_in[3];
  const int*   left = (const int*)d_in[4];
  const int*   asp  = (const int*)d_in[5];
  const int*   tl   = (const int*)d_in[6];
  float* out = (float*)d_out;
  float* ws  = (float*)d_ws;

  const size_t SZ = (size_t)NB*NLQ*ND;
  float* bufA = ws;                     // P (fp16, packed per tile) -> h1 (block-local overwrite)
  float* bufB = ws + SZ;                // fp16 hT plane; later Hasp/ybuf/hp/R/Wt15
  float* ws2  = ws + 2*SZ;
  float* tpart= ws2;                    // 4*32768
  float* T    = tpart + 4*32768;        // 163840
  float* g    = T + 163840;             // 65536
  float* scal = g + 65536;              // 16
  float* v    = scal + 16;              // 2560
  float* sbuf = v + 2560;               // 32768
  ushort_t* w0th = (ushort_t*)(sbuf + 32768);  // DD ushorts (layer-0 Wt fp16) in proven 1MB slot

  ushort_t* hTH = (ushort_t*)bufB;             // NB*HTB fp16

  float* Hasp = bufB;                   // reuse after k_attn0
  float* ybuf = Hasp + (size_t)5*MN;
  float* hp   = ybuf + (size_t)5*MN;
  float* R    = hp   + (size_t)5*MN;    // MN floats
  ushort_t* wt15h = (ushort_t*)(R + MN);       // 5*DD ushorts

  k_scal<<<NLAYERS, 256, 0, stream>>>(ast, scal);
  k_wa2<<<5*128, 256, 0, stream>>>(Wst, ast, v);
  k_wcvt<<<64, 256, 0, stream>>>(Wst, w0th);

  // layer 0: posw fused in A-stage; emits fp16 plane + fp16 pair-scores P + t-partials
  k_gemm_t<<<(NB*NLQ/128)*(ND/128), 256, 0, stream>>>(x, w0th,
      (unsigned int*)hTH, (ushort_t*)bufA, tpart, ast + ND, scal, left, asp, tl);
  k_attn0<<<NB*8, 256, 0, stream>>>(hTH, adj, tpart, left, asp, tl, bufA);

  // layers 1..5 on aspect rows only
  k_wcvt<<<5*64, 256, 0, stream>>>(Wst + DD, wt15h);
  k_tv<<<NB*NLQ/4, 256, 0, stream>>>(bufA, v, T);
  k_rows<<<NB, 256, 0, stream>>>(bufA, left, asp, R);
  k_gemm_b<<<5*32, 256, 0, stream>>>(R, 0L, wt15h, Hasp);
  k_att5<<<5*NB, 256, 0, stream>>>(bufA, Hasp, T, adj, scal, left, asp, ybuf);
  k_gemm_b<<<5*32, 256, 0, stream>>>(ybuf, (long)MN, wt15h, hp);
  k_g<<<NB, 256, 0, stream>>>(hp, asp, g);

  // final attention over original x
  k_dot<<<NB*NLQ/4, 256, 0, stream>>>(x, g, sbuf);
  k_out<<<NB*4, 256, 0, stream>>>(x, sbuf, out);
}

// Round 15
// 208.614 us; speedup vs baseline: 1.5786x; 1.0261x over previous
//
#include <hip/hip_runtime.h>

#define NB 128
#define NLQ 256   // sequence length L
#define ND 512    // feature dim D
#define NLAYERS 6
#define DD (ND*ND)
#define MN (1024*ND)
#define HTB 131072   // fp16 elems per batch in hT plane: 512*256

typedef _Float16 f16x8 __attribute__((ext_vector_type(8)));
typedef __fp16 fp16x2 __attribute__((ext_vector_type(2)));
typedef _Float16 f16x4v __attribute__((ext_vector_type(4)));
typedef float f32x4 __attribute__((ext_vector_type(4)));
typedef unsigned int u32x2 __attribute__((ext_vector_type(2)));
typedef unsigned int u32x4 __attribute__((ext_vector_type(4)));
typedef unsigned short ushort_t;

#define GLOAD16(gp, lp) __builtin_amdgcn_global_load_lds( \
    (const __attribute__((address_space(1))) void*)(gp), \
    (__attribute__((address_space(3))) void*)(lp), 16, 0, 0)

__device__ __forceinline__ float wave_max(float v){
  #pragma unroll
  for(int off=32; off; off>>=1) v = fmaxf(v, __shfl_xor(v, off));
  return v;
}
__device__ __forceinline__ float wave_sum(float v){
  #pragma unroll
  for(int off=32; off; off>>=1) v += __shfl_xor(v, off);
  return v;
}
// pack two fp32 into one dword of fp16 (v_cvt_pkrtz_f16_f32, single instr)
__device__ __forceinline__ unsigned int pk16(float a, float b){
  fp16x2 h = __builtin_amdgcn_cvt_pkrtz(a, b);
  return __builtin_bit_cast(unsigned int, h);
}

__global__ __launch_bounds__(256) void k_scal(const float* __restrict__ a_stack,
                                              float* __restrict__ scal){
  int layer = blockIdx.x;
  const float* a = a_stack + (size_t)layer*2*ND;
  int t = threadIdx.x;
  float v0 = a[t];
  float v1 = a[256 + t];
  v0 = wave_sum(v0); v1 = wave_sum(v1);
  __shared__ float s0[4], s1[4];
  int wave = t>>6, lane = t&63;
  if(lane==0){ s0[wave]=v0; s1[wave]=v1; }
  __syncthreads();
  if(t==0){
    scal[layer*2+0] = s0[0]+s0[1]+s0[2]+s0[3];
    scal[layer*2+1] = s1[0]+s1[1]+s1[2]+s1[3];
  }
}

// v_l[i] = dot(W_{l+1}[i,:], a2_{l+1})
__global__ __launch_bounds__(256) void k_wa2(const float* __restrict__ Wst,
                                             const float* __restrict__ ast,
                                             float* __restrict__ v){
  int l  = blockIdx.x >> 7;
  int rg = blockIdx.x & 127;
  int i  = rg*4 + (threadIdx.x>>6);
  int lane = threadIdx.x & 63;
  const float4* wr = (const float4*)(Wst + (size_t)(l+1)*DD + (size_t)i*ND);
  const float4* ar = (const float4*)(ast + (size_t)(l+1)*2*ND + ND);
  float4 w0=wr[lane], w1=wr[lane+64], a0=ar[lane], a1=ar[lane+64];
  float d = w0.x*a0.x + w0.y*a0.y + w0.z*a0.z + w0.w*a0.w
          + w1.x*a1.x + w1.y*a1.y + w1.z*a1.z + w1.w*a1.w;
  d = wave_sum(d);
  if(lane==0) v[l*ND + i] = d;
}

// transpose + convert W layers to single fp16 plane Wt[n][k]. One 64x64 tile per block.
__global__ __launch_bounds__(256) void k_wcvt(const float* __restrict__ Wsrc,
                                              ushort_t* __restrict__ Ho){
  __shared__ float CT[64][65];
  int bid = blockIdx.x;
  int l  = bid >> 6;
  int kt = (bid >> 3) & 7, nt = bid & 7;
  const float* Wl = Wsrc + (size_t)l*DD;
  int t = threadIdx.x;
  int r = t >> 2, c4 = (t&3)*16;
  #pragma unroll
  for(int u=0;u<4;u++){
    float4 vv = *(const float4*)(Wl + (size_t)(kt*64+r)*ND + nt*64 + c4 + u*4);
    CT[r][c4+u*4+0]=vv.x; CT[r][c4+u*4+1]=vv.y;
    CT[r][c4+u*4+2]=vv.z; CT[r][c4+u*4+3]=vv.w;
  }
  __syncthreads();
  int n = t >> 2, kc = t & 3;
  unsigned int o[8];
  #pragma unroll
  for(int j=0;j<8;j++)
    o[j] = pk16(CT[kc*16 + 2*j][n], CT[kc*16 + 2*j + 1][n]);
  ushort_t* dh = Ho + (size_t)l*DD + (size_t)(nt*64+n)*ND + kt*64 + kc*16;
  *(u32x4*)(dh)     = (u32x4){o[0],o[1],o[2],o[3]};
  *(u32x4*)(dh + 8) = (u32x4){o[4],o[5],o[6],o[7]};
}

// ---- fp16 MFMA GEMM tile, BK=64, 512 threads (8 waves, 2x4), wave tile 64x32 ----
// C[128x128] = A[128x512]@W[512x128]; W pre-converted/transposed fp16 Wt[n][k].
// MODE=0: C row-major [M][512].
// MODE=1: posw fused into A-stage; outputs transposed fp16 plane hP[b][d][i],
//         Pscore fp16 (packed per tile), t-partials tp4.
#define ROWB2 144   // 64 fp16 = 128B data + 16B pad
template<int MODE>
__device__ __forceinline__ void gemm_tile(const float* __restrict__ A,
                                          const ushort_t* __restrict__ Wth,
                                          float* __restrict__ C,
                                          unsigned int* __restrict__ hP,
                                          ushort_t* __restrict__ Pbuf,
                                          float* __restrict__ tp4,
                                          const float* __restrict__ a2,
                                          const float* __restrict__ scal,
                                          const int* __restrict__ left,
                                          const int* __restrict__ asp,
                                          const int* __restrict__ tl,
                                          int mtile, int ntile, unsigned char* lds){
  unsigned char* Ah = lds;                  // 128*144
  unsigned char* Bh = lds + 128*ROWB2;      // 128*144

  int t = threadIdx.x;                      // 0..511
  int m0 = mtile*128, n0 = ntile*128;
  int lane = t & 63, wid = t >> 6;          // wid 0..7
  int wr = wid >> 2, wcq = wid & 3;         // 2x4 wave grid
  int lrow = lane & 15, kb = lane >> 4;

  f32x4 acc[4][2];
  #pragma unroll
  for(int mi=0;mi<4;mi++)
    #pragma unroll
    for(int ni=0;ni<2;ni++)
      acc[mi][ni] = (f32x4){0.f,0.f,0.f,0.f};

  int a_row = t >> 4;       // 0..31 (+u*32, 4 u's)
  int a_sl  = t & 15;       // float4 slot within 64-k row
  int w_n   = t >> 3;       // 0..63 (+u*64, 2 u's)
  int w_sl  = t & 7;        // 16B slot

  float wgt_[4] = {1.f,1.f,1.f,1.f};
  if(MODE == 1){
    int b = mtile >> 1;
    float lf=(float)left[b], aspf=(float)asp[b], tlf=(float)tl[b];
    float rr=lf+aspf-1.f, ctx=tlf-aspf;
    #pragma unroll
    for(int u=0;u<4;u++){
      float jf = (float)((mtile&1)*128 + a_row + u*32);
      float w;
      if(jf < lf)       w = 1.f-(lf-jf)/ctx;
      else if(jf <= rr) w = 0.f;
      else if(jf < tlf) w = 1.f-(jf-rr)/ctx;
      else              w = 0.f;
      wgt_[u] = w;
    }
  }

  float4 pa[4];
  u32x4 pwh[2];

  #pragma unroll
  for(int u=0;u<4;u++)
    pa[u] = *(const float4*)(A + (size_t)(m0 + a_row + u*32)*ND + a_sl*4);
  #pragma unroll
  for(int u=0;u<2;u++)
    pwh[u] = *(const u32x4*)(Wth + (size_t)(n0 + w_n + u*64)*ND + w_sl*8);

  for(int k0=0; k0<ND; k0+=64){
    #pragma unroll
    for(int u=0;u<4;u++){
      unsigned int c0 = pk16(pa[u].x*wgt_[u], pa[u].y*wgt_[u]);
      unsigned int c1 = pk16(pa[u].z*wgt_[u], pa[u].w*wgt_[u]);
      *(u32x2*)(Ah + (a_row + u*32)*ROWB2 + a_sl*8) = (u32x2){c0, c1};
    }
    #pragma unroll
    for(int u=0;u<2;u++)
      *(u32x4*)(Bh + (w_n + u*64)*ROWB2 + w_sl*16) = pwh[u];
    __syncthreads();

    if(k0 + 64 < ND){
      int kn = k0 + 64;
      #pragma unroll
      for(int u=0;u<4;u++)
        pa[u] = *(const float4*)(A + (size_t)(m0 + a_row + u*32)*ND + kn + a_sl*4);
      #pragma unroll
      for(int u=0;u<2;u++)
        pwh[u] = *(const u32x4*)(Wth + (size_t)(n0 + w_n + u*64)*ND + kn + w_sl*8);
    }

    #pragma unroll
    for(int ks=0; ks<2; ks++){
      f16x8 ah[4], bh[2];
      #pragma unroll
      for(int mi=0;mi<4;mi++)
        ah[mi] = *(const f16x8*)(Ah + (wr*64 + mi*16 + lrow)*ROWB2 + ks*64 + kb*16);
      #pragma unroll
      for(int ni=0;ni<2;ni++)
        bh[ni] = *(const f16x8*)(Bh + (wcq*32 + ni*16 + lrow)*ROWB2 + ks*64 + kb*16);
      #pragma unroll
      for(int mi=0;mi<4;mi++)
        #pragma unroll
        for(int ni=0;ni<2;ni++)
          acc[mi][ni] = __builtin_amdgcn_mfma_f32_16x16x32_f16(ah[mi], bh[ni], acc[mi][ni], 0,0,0);
    }
    __syncthreads();
  }

  int rg = lane >> 4;
  int cc = lane & 15;
  if(MODE == 0){
    #pragma unroll
    for(int mi=0;mi<4;mi++)
      #pragma unroll
      for(int ni=0;ni<2;ni++){
        int col = n0 + wcq*32 + ni*16 + cc;
        #pragma unroll
        for(int q=0;q<4;q++){
          int row = m0 + wr*64 + mi*16 + rg*4 + q;
          C[(size_t)row*ND + col] = acc[mi][ni][q];
        }
      }
  } else {
    float S0 = scal[0], S1 = scal[1];
    float* CT = (float*)lds;   // 64*130 floats = 33280 B (fits in 36864 staging LDS)
    int b = m0 >> 8;
    int ibase = m0 & 255;
    int tr   = t >> 2;        // 0..127 (i row for t-partial)
    int tch  = t & 3;
    float tpsum = 0.f;
    #pragma unroll
    for(int p=0;p<2;p++){
      if((wcq>>1) == p){
        #pragma unroll
        for(int mi=0;mi<4;mi++)
          #pragma unroll
          for(int ni=0;ni<2;ni++)
            #pragma unroll
            for(int q=0;q<4;q++)
              CT[((wcq&1)*32 + ni*16 + cc)*130 + wr*64 + mi*16 + rg*4 + q] = acc[mi][ni][q];
      }
      __syncthreads();
      // transposed fp16 plane [b][d][i]
      int lcol = t >> 6;                 // 0..7
      int lrow2 = (t & 63)*2;            // i pair
      #pragma unroll
      for(int u=0;u<8;u++){
        int c = lcol + u*8;
        float2 v2 = *(float2*)&CT[c*130 + lrow2];
        size_t uidx = ((size_t)b*HTB + (size_t)(n0 + p*64 + c)*256 + ibase + lrow2) >> 1;
        hP[uidx] = pk16(v2.x, v2.y);
      }
      // Pscore: pair-reduced scores, fp16, packed into the (b,itile) h1 region
      {
        int cpr = t & 31;
        int rq  = t >> 5;                // 0..15
        #pragma unroll
        for(int rr2=0; rr2<8; rr2++){
          int row = rq*8 + rr2;          // 0..127
          float pval = S0*CT[(2*cpr)*130 + row] + S1*CT[(2*cpr+1)*130 + row];
          int ig = ibase + row;
          _Float16 ph = (_Float16)pval;
          size_t addr = (size_t)b*262144 + (size_t)(ig>>5)*32768
                      + (size_t)(ig&31)*256 + (n0>>1) + p*32 + cpr;
          Pbuf[addr] = __builtin_bit_cast(unsigned short, ph);
        }
      }
      // t-partial over this 64-d slab
      #pragma unroll
      for(int cc2=0; cc2<16; cc2++){
        int c = tch*16 + cc2;
        tpsum = fmaf(CT[c*130 + tr], a2[n0 + p*64 + c], tpsum);
      }
      __syncthreads();
    }
    tpsum += __shfl_xor(tpsum, 1);
    tpsum += __shfl_xor(tpsum, 2);
    if(tch == 0) tp4[(n0>>7)*32768 + m0 + tr] = tpsum;
  }
}

__global__ __launch_bounds__(512) void k_gemm_t(const float* __restrict__ A,
                                                const ushort_t* __restrict__ Wth,
                                                unsigned int* __restrict__ hP,
                                                ushort_t* __restrict__ Pbuf,
                                                float* __restrict__ tp4,
                                                const float* __restrict__ a2,
                                                const float* __restrict__ scal,
                                                const int* __restrict__ left,
                                                const int* __restrict__ asp,
                                                const int* __restrict__ tl){
  __shared__ unsigned char lds[2*128*ROWB2];   // 36864 B
  // XCD swizzle: 4 n-tiles of each m-tile within 32 consecutive bids, all same (bid mod 8)
  int bid = blockIdx.x;
  int ntile = (bid >> 3) & 3;
  int mtile = (bid & 7) | ((bid >> 5) << 3);
  gemm_tile<1>(A, Wth, nullptr, hP, Pbuf, tp4, a2, scal, left, asp, tl,
               mtile, ntile, lds);
}

__global__ __launch_bounds__(512) void k_gemm_b(const float* __restrict__ Abase, long aStride,
                                                const ushort_t* __restrict__ Wth,
                                                float* __restrict__ Cbase){
  __shared__ unsigned char lds[2*128*ROWB2];
  int l  = blockIdx.x >> 5;
  int tb = blockIdx.x & 31;
  gemm_tile<0>(Abase + (size_t)l*aStride, Wth + (size_t)l*DD,
               Cbase + (size_t)l*MN, nullptr, nullptr, nullptr,
               nullptr, nullptr, nullptr, nullptr, nullptr, tb>>2, tb&3, lds);
}

// layer-0 attention: coalesced fp16-P softmax (lanes=j, adj direct int4)
// + MFMA aggregation (att fp16, h plane fp16, 1 MFMA/frag) with global_load_lds B staging.
__global__ __launch_bounds__(256) void k_attn0(
    const ushort_t* __restrict__ hTH,
    const int* __restrict__ adj,
    const float* __restrict__ tpart,
    const int* __restrict__ left, const int* __restrict__ asp, const int* __restrict__ tl,
    float* __restrict__ PA){
  __shared__ unsigned char attH[32*512];   // fp16 att [32 i][256 j], XOR-swizzled
  __shared__ unsigned char BsH[16384];     // staged fp16 plane [256 d][32 j] linear 64B rows

  int bid = blockIdx.x;
  int b  = bid & 127;      // 8 blocks of batch b land on same XCD
  int ic = bid >> 7;
  int i0 = ic*32;
  int tid = threadIdx.x;
  int lane = tid & 63, w = tid >> 6;
  const ushort_t* HH = hTH + (size_t)b*HTB;
  const ushort_t* Pt = (const ushort_t*)PA + (size_t)b*262144 + (size_t)ic*32768;

  // ---- phase 1: softmax, lanes = j (4 j's per lane) ----
  float t0v=0.f, t1v=0.f, t2v=0.f, t3v=0.f;
  #pragma unroll
  for(int nt=0; nt<4; nt++){
    float4 tv = ((const float4*)(tpart + nt*32768 + b*256))[lane];
    t0v += tv.x; t1v += tv.y; t2v += tv.z; t3v += tv.w;
  }

  for(int rr=0; rr<8; rr++){
    int il = w*8 + rr;         // 0..31
    int i  = i0 + il;
    f16x4v pv = *(const f16x4v*)(Pt + il*256 + lane*4);
    int4 av = ((const int4*)(adj + ((size_t)b*NLQ + i)*NLQ))[lane];
    float e0 = fmaxf((float)pv[0] + t0v, 0.f);
    float e1 = fmaxf((float)pv[1] + t1v, 0.f);
    float e2 = fmaxf((float)pv[2] + t2v, 0.f);
    float e3 = fmaxf((float)pv[3] + t3v, 0.f);
    float m = -3.0e38f;
    if(av.x>0) m = e0;
    if(av.y>0) m = fmaxf(m, e1);
    if(av.z>0) m = fmaxf(m, e2);
    if(av.w>0) m = fmaxf(m, e3);
    m = wave_max(m);
    float p0 = (av.x>0) ? __expf(e0-m) : 0.f;
    float p1 = (av.y>0) ? __expf(e1-m) : 0.f;
    float p2 = (av.z>0) ? __expf(e2-m) : 0.f;
    float p3 = (av.w>0) ? __expf(e3-m) : 0.f;
    float s = wave_sum(p0+p1+p2+p3);
    float inv = 1.f/s;
    unsigned int w0 = pk16(p0*inv, p1*inv);
    unsigned int w1 = pk16(p2*inv, p3*inv);
    int off = il*512 + ((lane*8) ^ ((il&7)<<4));
    *(u32x2*)(attH + off) = (u32x2){w0,w1};
  }

  // ---- phase 2: O[i][d] = att @ h via MFMA; B staged via global_load_lds ----
  int wm = w >> 1, wn = w & 1;
  int lrow = lane & 15, kb = lane >> 4;
  int rg = lane >> 4, cc = lane & 15;
  float lf=(float)left[b], aspf=(float)asp[b], tlf=(float)tl[b];
  float rrv=lf+aspf-1.f, ctx=tlf-aspf;
  int arow = wm*16 + lrow;
  int aswz = (arow&7)<<4;

  for(int dp=0; dp<2; dp++){
    int d0 = dp*256;
    f32x4 acc[8];
    #pragma unroll
    for(int ni=0;ni<8;ni++) acc[ni] = (f32x4){0.f,0.f,0.f,0.f};
    for(int ks=0; ks<8; ks++){
      int j0 = ks*32;
      __syncthreads();   // previous tile fully consumed (also orders att writes)
      #pragma unroll
      for(int u=0;u<4;u++){
        int chunk = (u*4 + w)*64 + lane;
        int row = chunk >> 2, sl = chunk & 3;
        GLOAD16(HH + (size_t)(d0+row)*256 + j0 + sl*8, BsH + (u*4+w)*1024);
      }
      __syncthreads();   // loads landed
      int aoff = arow*512 + ((j0*2 + kb*16) ^ aswz);
      f16x8 ah = *(const f16x8*)(attH + aoff);
      #pragma unroll
      for(int ni=0; ni<8; ni++){
        f16x8 bh = *(const f16x8*)(BsH + (wn*128 + ni*16 + lrow)*64 + kb*16);
        acc[ni] = __builtin_amdgcn_mfma_f32_16x16x32_f16(ah, bh, acc[ni], 0,0,0);
      }
    }
    #pragma unroll
    for(int q=0;q<4;q++){
      int row = i0 + wm*16 + rg*4 + q;
      float fi = (float)row;
      float wgt;
      if(fi < lf)        wgt = 1.f-(lf-fi)/ctx;
      else if(fi <= rrv) wgt = 0.f;
      else if(fi < tlf)  wgt = 1.f-(fi-rrv)/ctx;
      else               wgt = 0.f;
      #pragma unroll
      for(int ni=0;ni<8;ni++){
        int col = d0 + wn*128 + ni*16 + cc;
        PA[((size_t)b*NLQ + row)*ND + col] = wgt*fmaxf(acc[ni][q], 0.f);
      }
    }
  }
}

// T[l][b*256+j] = h1[b,j,:] . v_l
__global__ __launch_bounds__(256) void k_tv(const float* __restrict__ h1,
                                            const float* __restrict__ v,
                                            float* __restrict__ T){
  int row  = blockIdx.x*4 + (threadIdx.x>>6);
  int lane = threadIdx.x & 63;
  const float4* hr = (const float4*)(h1 + (size_t)row*ND);
  float4 h0 = hr[lane], h1v = hr[lane+64];
  float s0,s1,s2,s3,s4;
  #define DOTV(SL, L) { \
    const float4* vr = (const float4*)(v + (L)*ND); \
    float4 v0 = vr[lane], v1 = vr[lane+64]; \
    float dd = h0.x*v0.x+h0.y*v0.y+h0.z*v0.z+h0.w*v0.w \
             + h1v.x*v1.x+h1v.y*v1.y+h1v.z*v1.z+h1v.w*v1.w; \
    SL = wave_sum(dd); }
  DOTV(s0,0) DOTV(s1,1) DOTV(s2,2) DOTV(s3,3) DOTV(s4,4)
  #undef DOTV
  if(lane==0){
    T[0*32768 + row]=s0; T[1*32768 + row]=s1; T[2*32768 + row]=s2;
    T[3*32768 + row]=s3; T[4*32768 + row]=s4;
  }
}

__global__ __launch_bounds__(256) void k_rows(const float* __restrict__ h1,
                                              const int* __restrict__ left, const int* __restrict__ asp,
                                              float* __restrict__ R){
  int b = blockIdx.x;
  int nk = asp[b], l0 = left[b];
  const float4* src = (const float4*)(h1 + (size_t)b*NLQ*ND);
  float4* dst = (float4*)(R + (size_t)b*8*ND);
  #pragma unroll
  for(int u=0; u<4; u++){
    int f4 = threadIdx.x + u*256;
    int k = f4 >> 7, c = f4 & 127;
    float4 val = (k<nk) ? src[(size_t)(l0+k)*128 + c] : (float4){0.f,0.f,0.f,0.f};
    dst[f4] = val;
  }
}

// one block per (layer, batch): 5 aspect-row atts + y = att @ h1.
// bid = l*128 + b  ->  all 5 layer-blocks of batch b on same XCD (128 % 8 == 0).
__global__ __launch_bounds__(256) void k_att5(const float* __restrict__ h1,
    const float* __restrict__ Hasp, const float* __restrict__ T,
    const int* __restrict__ adj, const float* __restrict__ scal,
    const int* __restrict__ left, const int* __restrict__ asp,
    float* __restrict__ y){
  __shared__ float att[5][260];
  int b  = blockIdx.x & 127;
  int l  = blockIdx.x >> 7;
  int tid = threadIdx.x, lane = tid&63, w = tid>>6;
  int nk = asp[b], l0 = left[b];
  float S0 = scal[2*(l+1)], S1 = scal[2*(l+1)+1];

  for(int k = w; k < 5; k += 4){
    if(k < nk){
      const float2* hrow = (const float2*)(Hasp + (size_t)l*MN + (size_t)(b*8+k)*ND);
      const int* arow = adj + ((size_t)b*NLQ + (l0+k))*NLQ;
      const float* Tl = T + l*32768 + b*256;
      float e[4]; int av[4];
      float m = -3.0e38f;
      #pragma unroll
      for(int q=0;q<4;q++){
        int j = lane + 64*q;
        float2 hp = hrow[j];
        av[q] = arow[j];
        e[q] = fmaxf(S0*hp.x + S1*hp.y + Tl[j], 0.f);
        if(av[q] > 0) m = fmaxf(m, e[q]);
      }
      m = wave_max(m);
      float pp[4]; float s = 0.f;
      #pragma unroll
      for(int q=0;q<4;q++){
        pp[q] = (av[q] > 0) ? __expf(e[q]-m) : 0.f;
        s += pp[q];
      }
      s = wave_sum(s);
      float inv = 1.f/s;
      #pragma unroll
      for(int q=0;q<4;q++) att[k][lane+64*q] = pp[q]*inv;
    } else {
      #pragma unroll
      for(int q=0;q<4;q++) att[k][lane+64*q] = 0.f;
    }
  }
  __syncthreads();

  int d = tid;
  const float* hb = h1 + (size_t)b*NLQ*ND;
  float ax[5] = {0,0,0,0,0}, ay[5] = {0,0,0,0,0};
  for(int jj=0; jj<NLQ; jj++){
    float hx = hb[(size_t)jj*ND + d];
    float hy = hb[(size_t)jj*ND + 256 + d];
    #pragma unroll
    for(int k=0;k<5;k++){
      float a = att[k][jj];
      ax[k] += a*hx;
      ay[k] += a*hy;
    }
  }
  float* yb = y + (size_t)l*MN + (size_t)b*8*ND;
  #pragma unroll
  for(int k=0;k<5;k++){
    yb[(size_t)k*ND + d]       = ax[k];
    yb[(size_t)k*ND + 256 + d] = ay[k];
  }
  #pragma unroll
  for(int u=0;u<6;u++) yb[5*ND + u*256 + tid] = 0.f;
}

__global__ __launch_bounds__(256) void k_g(const float* __restrict__ hp,
    const int* __restrict__ asp, float* __restrict__ g){
  int b = blockIdx.x, d = threadIdx.x;
  int nk = asp[b];
  float gx=0.f, gy=0.f;
  for(int l=0;l<5;l++){
    for(int k=0;k<nk;k++){
      const float* r = hp + (size_t)l*MN + (size_t)(b*8+k)*ND;
      gx += fmaxf(r[d], 0.f);
      gy += fmaxf(r[d+256], 0.f);
    }
  }
  g[b*ND + d]       = 0.2f*gx;
  g[b*ND + 256 + d] = 0.2f*gy;
}

__global__ __launch_bounds__(256) void k_dot(const float* __restrict__ x,
    const float* __restrict__ g, float* __restrict__ s){
  int row  = blockIdx.x*4 + (threadIdx.x>>6);
  int b    = row >> 8;
  int lane = threadIdx.x & 63;
  const float4* xr = (const float4*)(x + (size_t)row*ND);
  const float4* gr = (const float4*)(g + (size_t)b*ND);
  float4 x0=xr[lane], x1=xr[lane+64], g0=gr[lane], g1=gr[lane+64];
  float d = x0.x*g0.x + x0.y*g0.y + x0.z*g0.z + x0.w*g0.w
          + x1.x*g1.x + x1.y*g1.y + x1.z*g1.z + x1.w*g1.w;
  d = wave_sum(d);
  if(lane==0) s[row] = d;
}

__global__ __launch_bounds__(256) void k_out(const float* __restrict__ x,
    const float* __restrict__ s, float* __restrict__ out){
  int b  = blockIdx.x >> 2;
  int ch = blockIdx.x & 3;
  int tid = threadIdx.x, lane = tid&63, w = tid>>6;
  __shared__ float red[4];
  __shared__ float alpha[NLQ];
  __shared__ float part[128];
  float sv = s[b*NLQ + tid];
  float m = wave_max(sv);
  if(lane==0) red[w] = m;
  __syncthreads();
  m = fmaxf(fmaxf(red[0],red[1]), fmaxf(red[2],red[3]));
  float p = __expf(sv - m);
  float su = wave_sum(p);
  __syncthreads();
  if(lane==0) red[w] = su;
  __syncthreads();
  su = red[0]+red[1]+red[2]+red[3];
  alpha[tid] = p/su;
  __syncthreads();
  int d = ch*128 + (tid & 127);
  int half = tid >> 7;
  const float* xb = x + (size_t)b*NLQ*ND;
  float acc = 0.f;
  for(int mm = half*128; mm < half*128 + 128; mm++)
    acc += alpha[mm] * xb[(size_t)mm*ND + d];
  if(half) part[tid & 127] = acc;
  __syncthreads();
  if(!half) out[(size_t)b*ND + d] = acc + part[tid & 127];
}

extern "C" void kernel_launch(void* const* d_in, const int* in_sizes, int n_in,
                              void* d_out, int out_size, void* d_ws, size_t ws_size,
                              hipStream_t stream){
  const float* x    = (const float*)d_in[0];
  const float* Wst  = (const float*)d_in[1];
  const float* ast  = (const float*)d_in[2];
  const int*   adj  = (const int*)d_in[3];
  const int*   left = (const int*)d_in[4];
  const int*   asp  = (const int*)d_in[5];
  const int*   tl   = (const int*)d_in[6];
  float* out = (float*)d_out;
  float* ws  = (float*)d_ws;

  const size_t SZ = (size_t)NB*NLQ*ND;
  float* bufA = ws;                     // P (fp16, packed per tile) -> h1 (block-local overwrite)
  float* bufB = ws + SZ;                // fp16 hT plane; later Hasp/ybuf/hp/R/Wt15
  float* ws2  = ws + 2*SZ;
  float* tpart= ws2;                    // 4*32768
  float* T    = tpart + 4*32768;        // 163840
  float* g    = T + 163840;             // 65536
  float* scal = g + 65536;              // 16
  float* v    = scal + 16;              // 2560
  float* sbuf = v + 2560;               // 32768
  ushort_t* w0th = (ushort_t*)(sbuf + 32768);  // DD ushorts (layer-0 Wt fp16) in proven 1MB slot

  ushort_t* hTH = (ushort_t*)bufB;             // NB*HTB fp16

  float* Hasp = bufB;                   // reuse after k_attn0
  float* ybuf = Hasp + (size_t)5*MN;
  float* hp   = ybuf + (size_t)5*MN;
  float* R    = hp   + (size_t)5*MN;    // MN floats
  ushort_t* wt15h = (ushort_t*)(R + MN);       // 5*DD ushorts

  k_scal<<<NLAYERS, 256, 0, stream>>>(ast, scal);
  k_wa2<<<5*128, 256, 0, stream>>>(Wst, ast, v);
  k_wcvt<<<64, 256, 0, stream>>>(Wst, w0th);

  // layer 0: posw fused in A-stage; emits fp16 plane + fp16 pair-scores P + t-partials
  k_gemm_t<<<(NB*NLQ/128)*(ND/128), 512, 0, stream>>>(x, w0th,
      (unsigned int*)hTH, (ushort_t*)bufA, tpart, ast + ND, scal, left, asp, tl);
  k_attn0<<<NB*8, 256, 0, stream>>>(hTH, adj, tpart, left, asp, tl, bufA);

  // layers 1..5 on aspect rows only
  k_wcvt<<<5*64, 256, 0, stream>>>(Wst + DD, wt15h);
  k_tv<<<NB*NLQ/4, 256, 0, stream>>>(bufA, v, T);
  k_rows<<<NB, 256, 0, stream>>>(bufA, left, asp, R);
  k_gemm_b<<<5*32, 512, 0, stream>>>(R, 0L, wt15h, Hasp);
  k_att5<<<5*NB, 256, 0, stream>>>(bufA, Hasp, T, adj, scal, left, asp, ybuf);
  k_gemm_b<<<5*32, 512, 0, stream>>>(ybuf, (long)MN, wt15h, hp);
  k_g<<<NB, 256, 0, stream>>>(hp, asp, g);

  // final attention over original x
  k_dot<<<NB*NLQ/4, 256, 0, stream>>>(x, g, sbuf);
  k_out<<<NB*4, 256, 0, stream>>>(x, sbuf, out);
}